// Round 15
// baseline (109.864 us; speedup 1.0000x reference)
//
#include <hip/hip_runtime.h>
#include <hip/hip_bf16.h>

#define H 256
#define SEQ 10
#define C2LOG2E 2.8853900817779268f   // 2*log2(e)
#define LOG2E 1.4426950408889634f

typedef __attribute__((ext_vector_type(8))) short bf16x8;
typedef __attribute__((ext_vector_type(4))) float f32x4;

__device__ __forceinline__ unsigned short f2bf(float x) {
    union { float f; unsigned u; } v; v.f = x;
    unsigned r = v.u + 0x7fff + ((v.u >> 16) & 1);  // RNE
    return (unsigned short)(r >> 16);
}
__device__ __forceinline__ float bf2f(unsigned short b) {
    union { unsigned u; float f; } v; v.u = ((unsigned)b) << 16;
    return v.f;
}
__device__ __forceinline__ float fexp2(float x) {
    return __builtin_amdgcn_exp2f(x);
}

// prep: build Wt (pre-scaled by 2*log2e, transposed) only.
__global__ void prep_kernel(const float* __restrict__ W,
                            unsigned short* __restrict__ Wt) {
    int idx = blockIdx.x * 256 + threadIdx.x;
    if (idx >= H * 3 * H) return;
    int nn = idx / (3 * H), k = idx % (3 * H);
    Wt[idx] = f2bf(C2LOG2E * W[k * H + nn]);
}

// Merged launch: GEMM blocks + seg_start blocks (seg_start needs only seg_ids,
// so it rides along with the GEMM and overlaps it).
// GEMM: tile 64(m) x 256(n), 4 waves. A staged via LDS; B (Wt, L2-hot) direct
// to regs. EXP-TABLE EPILOGUES (Wt pre-scaled by 2*log2e):
//   ent blocks  : comb proj half <- bf16(exp2(acc))            [Ep table]
//   qpart blocks: Eq f32 table   <- exp2(acc + 2log2e*bias)    [Eq table]
// ent blocks also write staged bf16 A to comb em half.
__global__ void gemm_bf16_kernel(const float* __restrict__ entf,
                                 const int* __restrict__ sidx,
                                 const int* __restrict__ ridx,
                                 const float* __restrict__ rel,
                                 const unsigned short* __restrict__ Wt,
                                 const float* __restrict__ bias,
                                 unsigned short* __restrict__ comb,
                                 float* __restrict__ Eq,
                                 const int* __restrict__ seg_ids,
                                 int* __restrict__ seg_start,
                                 int n, int num_seg,
                                 int nEntBlk, int nQBlk, int M0, int M1) {
    int bid = blockIdx.x;
    if (bid >= nEntBlk + nQBlk) {
        // seg_start builder blocks
        int j = (bid - nEntBlk - nQBlk) * 256 + threadIdx.x;
        if (j >= n) return;
        int cur = seg_ids[j];
        int prev = (j == 0) ? -1 : seg_ids[j - 1];
        for (int s2 = prev + 1; s2 <= cur; s2++) seg_start[s2] = j;
        if (j == n - 1)
            for (int s2 = cur + 1; s2 <= num_seg; s2++) seg_start[s2] = n;
        return;
    }

    __shared__ unsigned short As[64][40];
    bool isEnt = bid < nEntBlk;
    int m0 = (isEnt ? bid : (bid - nEntBlk)) * 64;
    int M = isEnt ? M0 : M1;
    int K = isEnt ? H : 2 * H;
    int k0 = isEnt ? 0 : H;

    int t = threadIdx.x;
    int sr = t >> 2;          // 0..63
    int sc = (t & 3) * 8;     // 0/8/16/24
    int wave = t >> 6, lane = t & 63;
    int lr = lane & 15, lg = lane >> 4;

    f32x4 acc[4][4];
#pragma unroll
    for (int i = 0; i < 4; i++)
#pragma unroll
        for (int jn = 0; jn < 4; jn++) acc[i][jn] = (f32x4){0.f, 0.f, 0.f, 0.f};

    const unsigned short* bp[4];
#pragma unroll
    for (int bn = 0; bn < 4; bn++)
        bp[bn] = Wt + (size_t)(wave * 64 + bn * 16 + lr) * (3 * H) + k0 + lg * 8;

    for (int kk = 0; kk < K; kk += 32) {
        bf16x8 av = {};
        int gm = m0 + sr;
        if (gm < M) {
            const float* src;
            if (isEnt) {
                src = entf + (size_t)gm * H + kk + sc;
            } else {
                int k = kk + sc;
                src = (k < H) ? (entf + (size_t)sidx[gm] * H + k)
                              : (rel + (size_t)ridx[gm] * H + (k - H));
            }
            float4 f0 = *reinterpret_cast<const float4*>(src);
            float4 f1 = *reinterpret_cast<const float4*>(src + 4);
            av[0] = (short)f2bf(f0.x); av[1] = (short)f2bf(f0.y);
            av[2] = (short)f2bf(f0.z); av[3] = (short)f2bf(f0.w);
            av[4] = (short)f2bf(f1.x); av[5] = (short)f2bf(f1.y);
            av[6] = (short)f2bf(f1.z); av[7] = (short)f2bf(f1.w);
            if (isEnt)
                *reinterpret_cast<bf16x8*>(comb + (size_t)gm * 512 + 256 + kk + sc) = av;
        }
        *reinterpret_cast<bf16x8*>(&As[sr][sc]) = av;

        bf16x8 bfr[4];
#pragma unroll
        for (int bn = 0; bn < 4; bn++)
            bfr[bn] = *reinterpret_cast<const bf16x8*>(bp[bn] + kk);

        __syncthreads();
        bf16x8 afr[4];
#pragma unroll
        for (int am = 0; am < 4; am++)
            afr[am] = *reinterpret_cast<const bf16x8*>(&As[am * 16 + lr][lg * 8]);
#pragma unroll
        for (int am = 0; am < 4; am++)
#pragma unroll
            for (int bn = 0; bn < 4; bn++)
                acc[am][bn] = __builtin_amdgcn_mfma_f32_16x16x32_bf16(
                    afr[am], bfr[bn], acc[am][bn], 0, 0, 0);
        __syncthreads();
    }

#pragma unroll
    for (int bn = 0; bn < 4; bn++) {
        int col = wave * 64 + bn * 16 + lr;
        float bv = isEnt ? 0.f : C2LOG2E * bias[col];
#pragma unroll
        for (int am = 0; am < 4; am++) {
#pragma unroll
            for (int rr = 0; rr < 4; rr++) {
                int row = m0 + am * 16 + lg * 4 + rr;
                if (row < M) {
                    float ex = fexp2(acc[am][bn][rr] + bv);
                    if (isEnt)
                        comb[(size_t)row * 512 + col] = f2bf(ex);   // Ep (bf16)
                    else
                        Eq[(size_t)row * H + col] = ex;             // Eq (f32)
                }
            }
        }
    }
}

// Wave-per-segment, 4 waves/block, GRID-STRIDED over segments (2560 blocks =
// 10240 waves, ~2 segments each). Rationale: short-block configs hit a
// workgroup-dispatch-rate wall (~178 WG/us: r2 agg 20480/114us, r12 fused
// 10240/57.3us both = 178-180/us, occupancy pinned ~33% at every VALU mix).
// Fewer, longer blocks keep CUs fed from inside the kernel.
// Body: exp2(p'+q') = Ep*Eq (tables, no exp2 in loop); pair-rcp; gathers
// exec-predicated; proj+em prefetched 1-deep; ss/rr issued early; log2e
// folded into vm2/vsum; register-halving butterfly combine (12 shfl).
__global__ void __launch_bounds__(256)
fused_agg_kernel(const int* __restrict__ nbr_ids,
                 const int* __restrict__ seg_start,
                 const unsigned short* __restrict__ comb,
                 const float* __restrict__ Eq,
                 const float* __restrict__ v_s,
                 const float* __restrict__ ent_embeds,
                 const float* __restrict__ rel_embeds,
                 const int* __restrict__ s,
                 const int* __restrict__ r,
                 float* __restrict__ out, int num_seg) {
    int w = threadIdx.x >> 6;
    int lane = threadIdx.x & 63;
    int g = lane >> 4, li = lane & 15;
    int cb = li * 16;
    int c4 = lane * 4;
    int nwtot = gridDim.x * 4;

    // hoisted: v columns (pre-scaled by log2e — score in log2 domain)
    float vm2[16];   // -2*v*log2e
    float vsum = 0.f;  // log2e * sum(v)
    {
        const float4* vp = reinterpret_cast<const float4*>(v_s + cb);
#pragma unroll
        for (int k = 0; k < 4; k++) {
            float4 tv = vp[k];
            vm2[4 * k + 0] = -2.f * LOG2E * tv.x; vm2[4 * k + 1] = -2.f * LOG2E * tv.y;
            vm2[4 * k + 2] = -2.f * LOG2E * tv.z; vm2[4 * k + 3] = -2.f * LOG2E * tv.w;
            vsum += LOG2E * (tv.x + tv.y + tv.z + tv.w);
        }
    }

    for (int seg = blockIdx.x * 4 + w; seg < num_seg; seg += nwtot) {
        int start = seg_start[seg], end = seg_start[seg + 1];
        int b = seg / SEQ;
        float* orow = out + (size_t)seg * (3 * H);

        if (start == end) {
            float4 z = {0.f, 0.f, 0.f, 0.f};
            *reinterpret_cast<float4*>(orow + c4) = z;
            *reinterpret_cast<float4*>(orow + H + c4) = z;
            *reinterpret_cast<float4*>(orow + 2 * H + c4) = z;
            continue;
        }

        // issue ss/rr gathers early — consumed only at the end
        float4 ssv = *reinterpret_cast<const float4*>(ent_embeds + (size_t)s[b] * H + c4);
        float4 rrv = *reinterpret_cast<const float4*>(rel_embeds + (size_t)r[b] * H + c4);

        // Eq columns for this lane (f32, exact)
        float qv[16];
        {
            const float4* qp = reinterpret_cast<const float4*>(Eq + (size_t)b * H + cb);
#pragma unroll
            for (int k = 0; k < 4; k++) {
                float4 tq = qp[k];
                qv[4 * k + 0] = tq.x; qv[4 * k + 1] = tq.y;
                qv[4 * k + 2] = tq.z; qv[4 * k + 3] = tq.w;
            }
        }

        float acc[16];
#pragma unroll
        for (int k = 0; k < 16; k++) acc[k] = 0.f;
        float lpart = 0.f;

        int cc = end - start;
        int nitm = (cc + 3) >> 2;

        // prologue: predicated load of row j=g (Ep + em)
        bf16x8 p0 = {}, p1 = {}, e0 = {}, e1 = {};
        if (g < cc) {
            const unsigned short* row = comb + (size_t)nbr_ids[start + g] * 512 + cb;
            p0 = *reinterpret_cast<const bf16x8*>(row);
            p1 = *reinterpret_cast<const bf16x8*>(row + 8);
            e0 = *reinterpret_cast<const bf16x8*>(row + 256);
            e1 = *reinterpret_cast<const bf16x8*>(row + 264);
        }

        for (int ji = 0; ji < nitm; ji++) {
            // predicated prefetch of next row (Ep + em)
            bf16x8 p0n = {}, p1n = {}, e0n = {}, e1n = {};
            int jn = 4 * (ji + 1) + g;
            if (jn < cc) {
                const unsigned short* rown = comb + (size_t)nbr_ids[start + jn] * 512 + cb;
                p0n = *reinterpret_cast<const bf16x8*>(rown);
                p1n = *reinterpret_cast<const bf16x8*>(rown + 8);
                e0n = *reinterpret_cast<const bf16x8*>(rown + 256);
                e1n = *reinterpret_cast<const bf16x8*>(rown + 264);
            }

            // score: u = Ep*Eq, a = u+1; paired rcp (no exp2 in loop)
            float sa = 0.f, sb = 0.f;
#pragma unroll
            for (int k = 0; k < 8; k += 2) {
                float a0 = fmaf(bf2f((unsigned short)p0[k]), qv[k], 1.f);
                float a1 = fmaf(bf2f((unsigned short)p1[k]), qv[8 + k], 1.f);
                float num = vm2[k] * a1;
                num = fmaf(vm2[8 + k], a0, num);
                sa = fmaf(num, __builtin_amdgcn_rcpf(a0 * a1), sa);
                float b0 = fmaf(bf2f((unsigned short)p0[k + 1]), qv[k + 1], 1.f);
                float b1 = fmaf(bf2f((unsigned short)p1[k + 1]), qv[9 + k], 1.f);
                float numb = vm2[k + 1] * b1;
                numb = fmaf(vm2[9 + k], b0, numb);
                sb = fmaf(numb, __builtin_amdgcn_rcpf(b0 * b1), sb);
            }
            float s16 = sa + sb + vsum;      // log2-domain score
            s16 += __shfl_xor(s16, 1);
            s16 += __shfl_xor(s16, 2);
            s16 += __shfl_xor(s16, 4);
            s16 += __shfl_xor(s16, 8);
            float e = fexp2(s16);
            e = (4 * ji + g < cc) ? e : 0.f;
            lpart += e;
#pragma unroll
            for (int k = 0; k < 8; k++) {
                acc[k] = fmaf(e, bf2f((unsigned short)e0[k]), acc[k]);
                acc[8 + k] = fmaf(e, bf2f((unsigned short)e1[k]), acc[8 + k]);
            }
            p0 = p0n; p1 = p1n; e0 = e0n; e1 = e1n;
        }

        // lpart combine (all 64 lanes hold partials)
        lpart += __shfl_xor(lpart, 16);
        lpart += __shfl_xor(lpart, 32);
        float invl = 1.f / lpart;

        // register-halving butterfly: lane in group g ends with acc[4g..4g+3]
        int gb0 = g & 1, gb1 = g >> 1;
        float t1[8];
#pragma unroll
        for (int j = 0; j < 8; j++) {
            int sl0 = (j < 4) ? j : 4 + j;       // L0 = {0,1,2,3,8,9,10,11}
            int sl1 = sl0 + 4;                   // L1 = {4,5,6,7,12,13,14,15}
            float mine = gb0 ? acc[sl1] : acc[sl0];
            float opp  = gb0 ? acc[sl0] : acc[sl1];
            t1[j] = mine + __shfl_xor(opp, 16);
        }
        float4 o;
#pragma unroll
        for (int j = 0; j < 4; j++) {
            float mine = gb1 ? t1[4 + j] : t1[j];
            float opp  = gb1 ? t1[j] : t1[4 + j];
            float fin = (mine + __shfl_xor(opp, 32)) * invl;
            if (j == 0) o.x = fin;
            else if (j == 1) o.y = fin;
            else if (j == 2) o.z = fin;
            else o.w = fin;
        }
        *reinterpret_cast<float4*>(orow + cb + 4 * g) = o;
        *reinterpret_cast<float4*>(orow + H + c4) = ssv;
        *reinterpret_cast<float4*>(orow + 2 * H + c4) = rrv;
    }
}

extern "C" void kernel_launch(void* const* d_in, const int* in_sizes, int n_in,
                              void* d_out, int out_size, void* d_ws, size_t ws_size,
                              hipStream_t stream) {
    const int* s = (const int*)d_in[0];
    const int* r = (const int*)d_in[1];
    const int* nbr_ids = (const int*)d_in[2];
    const int* seg_ids = (const int*)d_in[3];
    const float* ent_embeds = (const float*)d_in[4];
    const float* rel_embeds = (const float*)d_in[5];
    const float* W_attn = (const float*)d_in[6];
    const float* b_attn = (const float*)d_in[7];
    const float* v_s = (const float*)d_in[8];
    float* out = (float*)d_out;

    int B = in_sizes[0];
    int N = in_sizes[2];
    int num_ent = in_sizes[4] / H;
    int num_seg = B * SEQ;

    char* ws = (char*)d_ws;
    unsigned short* comb = (unsigned short*)ws;                 // num_ent*512 (Ep|em)
    unsigned short* Wt = comb + (size_t)num_ent * 512;          // H*3H (pre-scaled)
    float* Eq = (float*)(Wt + (size_t)H * 3 * H);               // B*H f32 exp table
    int* seg_start = (int*)(Eq + (size_t)B * H);                // num_seg+1

    int nWt = (H * 3 * H + 255) / 256;       // 768
    prep_kernel<<<nWt, 256, 0, stream>>>(W_attn, Wt);

    int nEntBlk = (num_ent + 63) / 64;       // 313
    int nQBlk = B / 64;                      // 32
    int nSegBlk = (N + 255) / 256;           // 1280 (seg_start riders)
    gemm_bf16_kernel<<<nEntBlk + nQBlk + nSegBlk, 256, 0, stream>>>(
        ent_embeds, s, r, rel_embeds, Wt, b_attn, comb, Eq,
        seg_ids, seg_start, N, num_seg, nEntBlk, nQBlk, num_ent, B);

    fused_agg_kernel<<<2560, 256, 0, stream>>>(
        nbr_ids, seg_start, comb, Eq, v_s,
        ent_embeds, rel_embeds, s, r, out, num_seg);
}

// Round 16
// 99.383 us; speedup vs baseline: 1.1055x; 1.1055x over previous
//
#include <hip/hip_runtime.h>
#include <hip/hip_bf16.h>

#define H 256
#define SEQ 10
#define C2LOG2E 2.8853900817779268f   // 2*log2(e)
#define LOG2E 1.4426950408889634f

typedef __attribute__((ext_vector_type(8))) short bf16x8;
typedef __attribute__((ext_vector_type(4))) float f32x4;
typedef __attribute__((ext_vector_type(2))) float f32x2;

__device__ __forceinline__ unsigned short f2bf(float x) {
    union { float f; unsigned u; } v; v.f = x;
    unsigned r = v.u + 0x7fff + ((v.u >> 16) & 1);  // RNE
    return (unsigned short)(r >> 16);
}
__device__ __forceinline__ float bf2f(unsigned short b) {
    union { unsigned u; float f; } v; v.u = ((unsigned)b) << 16;
    return v.f;
}
__device__ __forceinline__ float fexp2(float x) {
    return __builtin_amdgcn_exp2f(x);
}
// unpack a packed bf16 pair (u32) -> f32x2 {lo, hi}
__device__ __forceinline__ f32x2 up2(unsigned u) {
    union { unsigned u32; float f; } lo, hi;
    lo.u32 = u << 16;
    hi.u32 = u & 0xffff0000u;
    f32x2 r; r.x = lo.f; r.y = hi.f;
    return r;
}

// Merged: blocks [0, nWt) build Wt (pre-scaled by 2*log2e, transposed);
// blocks [nWt, ...) build seg_start.
__global__ void prep_kernel(const float* __restrict__ W,
                            unsigned short* __restrict__ Wt,
                            const int* __restrict__ seg_ids,
                            int* __restrict__ seg_start,
                            int nWt, int n, int num_seg) {
    if ((int)blockIdx.x < nWt) {
        int idx = blockIdx.x * 256 + threadIdx.x;
        if (idx >= H * 3 * H) return;
        int nn = idx / (3 * H), k = idx % (3 * H);
        Wt[idx] = f2bf(C2LOG2E * W[k * H + nn]);
    } else {
        int j = (blockIdx.x - nWt) * 256 + threadIdx.x;
        if (j >= n) return;
        int cur = seg_ids[j];
        int prev = (j == 0) ? -1 : seg_ids[j - 1];
        for (int s2 = prev + 1; s2 <= cur; s2++) seg_start[s2] = j;
        if (j == n - 1)
            for (int s2 = cur + 1; s2 <= num_seg; s2++) seg_start[s2] = n;
    }
}

// Merged tiled bf16 MFMA GEMM, tile 64(m) x 256(n), 4 waves.
// A staged via LDS; B (Wt, L2-hot) direct to registers.
// EXP-TABLE EPILOGUES (Wt pre-scaled by 2*log2e):
//   ent blocks  : comb proj half <- bf16(exp2(acc))            [Ep table]
//   qpart blocks: Eq f32 table   <- exp2(acc + 2log2e*bias)    [Eq table]
// ent blocks also write staged bf16 A to comb em half.
__global__ void gemm_bf16_kernel(const float* __restrict__ entf,
                                 const int* __restrict__ sidx,
                                 const int* __restrict__ ridx,
                                 const float* __restrict__ rel,
                                 const unsigned short* __restrict__ Wt,
                                 const float* __restrict__ bias,
                                 unsigned short* __restrict__ comb,
                                 float* __restrict__ Eq,
                                 int nEntBlk, int M0, int M1) {
    __shared__ unsigned short As[64][40];
    bool isEnt = (int)blockIdx.x < nEntBlk;
    int m0 = (isEnt ? blockIdx.x : (blockIdx.x - nEntBlk)) * 64;
    int M = isEnt ? M0 : M1;
    int K = isEnt ? H : 2 * H;
    int k0 = isEnt ? 0 : H;

    int t = threadIdx.x;
    int sr = t >> 2;          // 0..63
    int sc = (t & 3) * 8;     // 0/8/16/24
    int wave = t >> 6, lane = t & 63;
    int lr = lane & 15, lg = lane >> 4;

    f32x4 acc[4][4];
#pragma unroll
    for (int i = 0; i < 4; i++)
#pragma unroll
        for (int jn = 0; jn < 4; jn++) acc[i][jn] = (f32x4){0.f, 0.f, 0.f, 0.f};

    const unsigned short* bp[4];
#pragma unroll
    for (int bn = 0; bn < 4; bn++)
        bp[bn] = Wt + (size_t)(wave * 64 + bn * 16 + lr) * (3 * H) + k0 + lg * 8;

    for (int kk = 0; kk < K; kk += 32) {
        bf16x8 av = {};
        int gm = m0 + sr;
        if (gm < M) {
            const float* src;
            if (isEnt) {
                src = entf + (size_t)gm * H + kk + sc;
            } else {
                int k = kk + sc;
                src = (k < H) ? (entf + (size_t)sidx[gm] * H + k)
                              : (rel + (size_t)ridx[gm] * H + (k - H));
            }
            float4 f0 = *reinterpret_cast<const float4*>(src);
            float4 f1 = *reinterpret_cast<const float4*>(src + 4);
            av[0] = (short)f2bf(f0.x); av[1] = (short)f2bf(f0.y);
            av[2] = (short)f2bf(f0.z); av[3] = (short)f2bf(f0.w);
            av[4] = (short)f2bf(f1.x); av[5] = (short)f2bf(f1.y);
            av[6] = (short)f2bf(f1.z); av[7] = (short)f2bf(f1.w);
            if (isEnt)
                *reinterpret_cast<bf16x8*>(comb + (size_t)gm * 512 + 256 + kk + sc) = av;
        }
        *reinterpret_cast<bf16x8*>(&As[sr][sc]) = av;

        bf16x8 bfr[4];
#pragma unroll
        for (int bn = 0; bn < 4; bn++)
            bfr[bn] = *reinterpret_cast<const bf16x8*>(bp[bn] + kk);

        __syncthreads();
        bf16x8 afr[4];
#pragma unroll
        for (int am = 0; am < 4; am++)
            afr[am] = *reinterpret_cast<const bf16x8*>(&As[am * 16 + lr][lg * 8]);
#pragma unroll
        for (int am = 0; am < 4; am++)
#pragma unroll
            for (int bn = 0; bn < 4; bn++)
                acc[am][bn] = __builtin_amdgcn_mfma_f32_16x16x32_bf16(
                    afr[am], bfr[bn], acc[am][bn], 0, 0, 0);
        __syncthreads();
    }

#pragma unroll
    for (int bn = 0; bn < 4; bn++) {
        int col = wave * 64 + bn * 16 + lr;
        float bv = isEnt ? 0.f : C2LOG2E * bias[col];
#pragma unroll
        for (int am = 0; am < 4; am++) {
#pragma unroll
            for (int rr = 0; rr < 4; rr++) {
                int row = m0 + am * 16 + lg * 4 + rr;
                if (row < M) {
                    float ex = fexp2(acc[am][bn][rr] + bv);
                    if (isEnt)
                        comb[(size_t)row * 512 + col] = f2bf(ex);   // Ep (bf16)
                    else
                        Eq[(size_t)row * H + col] = ex;             // Eq (f32)
                }
            }
        }
    }
}

// One wave per segment, 2 waves per block (best-measured structure, r12).
// Lane group g (16 lanes) handles neighbors j == 4*ji+g; lane covers 16 cols.
// Single pass, no max-subtraction. Hot loop: exp2(p'+q') = Ep*Eq (tables);
// pair-rcp:  v0/(u0+1)+v1/(u1+1) = (v0*a.y + v1*a.x)*rcp(a.x*a.y).
// PACKED MATH: a-pairs and acc-fma as f32x2 elementwise fma -> v_pk_fma_f32
// (halves those FMA slots, zero extra registers — pairs are renames).
// s_setprio(1) around compute, (0) while prefetch loads are in flight (T5).
// log2e folded into vm2/vsum (score in log2 domain, e = exp2(s)).
// Cross-group combine: register-halving butterfly (12 shfl).
// VGPR must stay <= 64 (occupancy cliff measured r14/r15: >64 costs ~35%).
__global__ void __launch_bounds__(128)
fused_agg_kernel(const int* __restrict__ nbr_ids,
                 const int* __restrict__ seg_start,
                 const unsigned short* __restrict__ comb,
                 const float* __restrict__ Eq,
                 const float* __restrict__ v_s,
                 const float* __restrict__ ent_embeds,
                 const float* __restrict__ rel_embeds,
                 const int* __restrict__ s,
                 const int* __restrict__ r,
                 float* __restrict__ out, int num_seg) {
    int seg = blockIdx.x * 2 + (threadIdx.x >> 6);
    if (seg >= num_seg) return;
    int lane = threadIdx.x & 63;
    int g = lane >> 4, li = lane & 15;
    int cb = li * 16;
    int c4 = lane * 4;
    int b = seg / SEQ;
    int start = seg_start[seg], end = seg_start[seg + 1];
    float* orow = out + (size_t)seg * (3 * H);

    if (start == end) {
        float4 z = {0.f, 0.f, 0.f, 0.f};
        *reinterpret_cast<float4*>(orow + c4) = z;
        *reinterpret_cast<float4*>(orow + H + c4) = z;
        *reinterpret_cast<float4*>(orow + 2 * H + c4) = z;
        return;
    }

    // issue ss/rr gathers early — consumed only at the end
    float4 ssv = *reinterpret_cast<const float4*>(ent_embeds + (size_t)s[b] * H + c4);
    float4 rrv = *reinterpret_cast<const float4*>(rel_embeds + (size_t)r[b] * H + c4);

    // v columns (log2e folded in)
    float vm2[16];      // -2*log2e*v
    float vsum = 0.f;   // log2e*sum(v)
    {
        const float4* vp = reinterpret_cast<const float4*>(v_s + cb);
#pragma unroll
        for (int k = 0; k < 4; k++) {
            float4 tv = vp[k];
            vm2[4 * k + 0] = -2.f * LOG2E * tv.x; vm2[4 * k + 1] = -2.f * LOG2E * tv.y;
            vm2[4 * k + 2] = -2.f * LOG2E * tv.z; vm2[4 * k + 3] = -2.f * LOG2E * tv.w;
            vsum += LOG2E * (tv.x + tv.y + tv.z + tv.w);
        }
    }

    // Eq columns as f32x2 pairs
    f32x2 qv2[8];
    {
        const float4* qp = reinterpret_cast<const float4*>(Eq + (size_t)b * H + cb);
#pragma unroll
        for (int k = 0; k < 4; k++) {
            float4 tq = qp[k];
            qv2[2 * k + 0] = (f32x2){tq.x, tq.y};
            qv2[2 * k + 1] = (f32x2){tq.z, tq.w};
        }
    }

    f32x2 acc2[8];
#pragma unroll
    for (int k = 0; k < 8; k++) acc2[k] = (f32x2){0.f, 0.f};
    float lpart = 0.f;

    int cc = end - start;
    int nitm = (cc + 3) >> 2;

    // prologue: predicated load of row j=g (Ep + em) as packed u32x4
    uint4 p0 = {}, p1 = {}, e0 = {}, e1 = {};
    if (g < cc) {
        const unsigned short* row = comb + (size_t)nbr_ids[start + g] * 512 + cb;
        p0 = *reinterpret_cast<const uint4*>(row);
        p1 = *reinterpret_cast<const uint4*>(row + 8);
        e0 = *reinterpret_cast<const uint4*>(row + 256);
        e1 = *reinterpret_cast<const uint4*>(row + 264);
    }

    const f32x2 one2 = (f32x2){1.f, 1.f};

    for (int ji = 0; ji < nitm; ji++) {
        // predicated prefetch of next row (Ep + em)
        uint4 p0n = {}, p1n = {}, e0n = {}, e1n = {};
        int jn = 4 * (ji + 1) + g;
        if (jn < cc) {
            const unsigned short* rown = comb + (size_t)nbr_ids[start + jn] * 512 + cb;
            p0n = *reinterpret_cast<const uint4*>(rown);
            p1n = *reinterpret_cast<const uint4*>(rown + 8);
            e0n = *reinterpret_cast<const uint4*>(rown + 256);
            e1n = *reinterpret_cast<const uint4*>(rown + 264);
        }

        __builtin_amdgcn_s_setprio(1);
        // score: u = Ep*Eq, a = u+1 (packed); paired rcp
        float sa = 0.f, sb = 0.f;
#define PAIR(comp, qj, vlo, vhi, dst)                                      \
        {                                                                  \
            f32x2 a = __builtin_elementwise_fma(up2(comp), qv2[qj], one2); \
            float num = vlo * a.y;                                         \
            num = fmaf(vhi, a.x, num);                                     \
            dst = fmaf(num, __builtin_amdgcn_rcpf(a.x * a.y), dst);        \
        }
        PAIR(p0.x, 0, vm2[0],  vm2[1],  sa)
        PAIR(p0.y, 1, vm2[2],  vm2[3],  sb)
        PAIR(p0.z, 2, vm2[4],  vm2[5],  sa)
        PAIR(p0.w, 3, vm2[6],  vm2[7],  sb)
        PAIR(p1.x, 4, vm2[8],  vm2[9],  sa)
        PAIR(p1.y, 5, vm2[10], vm2[11], sb)
        PAIR(p1.z, 6, vm2[12], vm2[13], sa)
        PAIR(p1.w, 7, vm2[14], vm2[15], sb)
#undef PAIR
        float s16 = sa + sb + vsum;      // log2-domain score
        s16 += __shfl_xor(s16, 1);
        s16 += __shfl_xor(s16, 2);
        s16 += __shfl_xor(s16, 4);
        s16 += __shfl_xor(s16, 8);
        float e = fexp2(s16);
        e = (4 * ji + g < cc) ? e : 0.f;
        lpart += e;
        f32x2 e2; e2.x = e; e2.y = e;
        acc2[0] = __builtin_elementwise_fma(e2, up2(e0.x), acc2[0]);
        acc2[1] = __builtin_elementwise_fma(e2, up2(e0.y), acc2[1]);
        acc2[2] = __builtin_elementwise_fma(e2, up2(e0.z), acc2[2]);
        acc2[3] = __builtin_elementwise_fma(e2, up2(e0.w), acc2[3]);
        acc2[4] = __builtin_elementwise_fma(e2, up2(e1.x), acc2[4]);
        acc2[5] = __builtin_elementwise_fma(e2, up2(e1.y), acc2[5]);
        acc2[6] = __builtin_elementwise_fma(e2, up2(e1.z), acc2[6]);
        acc2[7] = __builtin_elementwise_fma(e2, up2(e1.w), acc2[7]);
        __builtin_amdgcn_s_setprio(0);

        p0 = p0n; p1 = p1n; e0 = e0n; e1 = e1n;
    }

    // lpart combine (all 64 lanes hold partials)
    lpart += __shfl_xor(lpart, 16);
    lpart += __shfl_xor(lpart, 32);
    float invl = 1.f / lpart;

    // expand pairs to the scalar layout the butterfly expects (renames only)
    float acc[16];
#pragma unroll
    for (int j = 0; j < 8; j++) { acc[2 * j] = acc2[j].x; acc[2 * j + 1] = acc2[j].y; }

    // register-halving butterfly: lane in group g ends with acc[4g..4g+3]
    int gb0 = g & 1, gb1 = g >> 1;
    float t1[8];
#pragma unroll
    for (int j = 0; j < 8; j++) {
        int sl0 = (j < 4) ? j : 4 + j;       // L0 = {0,1,2,3,8,9,10,11}
        int sl1 = sl0 + 4;                   // L1 = {4,5,6,7,12,13,14,15}
        float mine = gb0 ? acc[sl1] : acc[sl0];
        float opp  = gb0 ? acc[sl0] : acc[sl1];
        t1[j] = mine + __shfl_xor(opp, 16);
    }
    float4 o;
#pragma unroll
    for (int j = 0; j < 4; j++) {
        float mine = gb1 ? t1[4 + j] : t1[j];
        float opp  = gb1 ? t1[j] : t1[4 + j];
        float fin = (mine + __shfl_xor(opp, 32)) * invl;
        if (j == 0) o.x = fin;
        else if (j == 1) o.y = fin;
        else if (j == 2) o.z = fin;
        else o.w = fin;
    }
    *reinterpret_cast<float4*>(orow + cb + 4 * g) = o;
    *reinterpret_cast<float4*>(orow + H + c4) = ssv;
    *reinterpret_cast<float4*>(orow + 2 * H + c4) = rrv;
}

extern "C" void kernel_launch(void* const* d_in, const int* in_sizes, int n_in,
                              void* d_out, int out_size, void* d_ws, size_t ws_size,
                              hipStream_t stream) {
    const int* s = (const int*)d_in[0];
    const int* r = (const int*)d_in[1];
    const int* nbr_ids = (const int*)d_in[2];
    const int* seg_ids = (const int*)d_in[3];
    const float* ent_embeds = (const float*)d_in[4];
    const float* rel_embeds = (const float*)d_in[5];
    const float* W_attn = (const float*)d_in[6];
    const float* b_attn = (const float*)d_in[7];
    const float* v_s = (const float*)d_in[8];
    float* out = (float*)d_out;

    int B = in_sizes[0];
    int N = in_sizes[2];
    int num_ent = in_sizes[4] / H;
    int num_seg = B * SEQ;

    char* ws = (char*)d_ws;
    unsigned short* comb = (unsigned short*)ws;                 // num_ent*512 (Ep|em)
    unsigned short* Wt = comb + (size_t)num_ent * 512;          // H*3H (pre-scaled)
    float* Eq = (float*)(Wt + (size_t)H * 3 * H);               // B*H f32 exp table
    int* seg_start = (int*)(Eq + (size_t)B * H);                // num_seg+1

    int nWt = (H * 3 * H + 255) / 256;       // 768
    int nSeg = (N + 255) / 256;              // 1280
    prep_kernel<<<nWt + nSeg, 256, 0, stream>>>(W_attn, Wt, seg_ids, seg_start,
                                                nWt, N, num_seg);

    int nEntBlk = (num_ent + 63) / 64;       // 313
    int nQBlk = B / 64;                      // 32
    gemm_bf16_kernel<<<nEntBlk + nQBlk, 256, 0, stream>>>(
        ent_embeds, s, r, rel_embeds, Wt, b_attn, comb, Eq,
        nEntBlk, num_ent, B);

    fused_agg_kernel<<<(num_seg + 1) / 2, 128, 0, stream>>>(
        nbr_ids, seg_start, comb, Eq, v_s,
        ent_embeds, rel_embeds, s, r, out, num_seg);
}

// Round 17
// 98.095 us; speedup vs baseline: 1.1200x; 1.0131x over previous
//
#include <hip/hip_runtime.h>
#include <hip/hip_bf16.h>

#define H 256
#define SEQ 10
#define C2LOG2E 2.8853900817779268f   // 2*log2(e)
#define LOG2E 1.4426950408889634f

typedef __attribute__((ext_vector_type(8))) short bf16x8;
typedef __attribute__((ext_vector_type(4))) float f32x4;

__device__ __forceinline__ unsigned short f2bf(float x) {
    union { float f; unsigned u; } v; v.f = x;
    unsigned r = v.u + 0x7fff + ((v.u >> 16) & 1);  // RNE
    return (unsigned short)(r >> 16);
}
__device__ __forceinline__ float bf2f(unsigned short b) {
    union { unsigned u; float f; } v; v.u = ((unsigned)b) << 16;
    return v.f;
}
__device__ __forceinline__ float fexp2(float x) {
    return __builtin_amdgcn_exp2f(x);
}

// prep: blocks [0, nTr) build Wt via LDS tile transpose (coalesced read AND
// write; the old scalar version read W at 1KB stride — fully uncoalesced).
// Wt[n][k] = bf16(2log2e * W[k][n]), row-major [H][3H].
// Blocks [nTr, ...) build seg_start.
__global__ void prep_kernel(const float* __restrict__ W,
                            unsigned short* __restrict__ Wt,
                            const int* __restrict__ seg_ids,
                            int* __restrict__ seg_start,
                            int nTr, int n, int num_seg) {
    if ((int)blockIdx.x < nTr) {
        __shared__ float tile[64][65];
        int tk = blockIdx.x % 12;   // k-tile (3H/64 = 12)
        int tn = blockIdx.x / 12;   // n-tile (H/64 = 4)
        int t = threadIdx.x;
        int rr = t >> 2;            // 0..63
        int rc = (t & 3) * 16;      // 0,16,32,48
        // coalesced read: row (tk*64+rr) of W, 16 floats starting at col tn*64+rc
        const float* src = W + (size_t)(tk * 64 + rr) * H + tn * 64 + rc;
        float4 a = *reinterpret_cast<const float4*>(src);
        float4 b = *reinterpret_cast<const float4*>(src + 4);
        float4 c = *reinterpret_cast<const float4*>(src + 8);
        float4 d = *reinterpret_cast<const float4*>(src + 12);
        tile[rr][rc + 0] = a.x;  tile[rr][rc + 1] = a.y;
        tile[rr][rc + 2] = a.z;  tile[rr][rc + 3] = a.w;
        tile[rr][rc + 4] = b.x;  tile[rr][rc + 5] = b.y;
        tile[rr][rc + 6] = b.z;  tile[rr][rc + 7] = b.w;
        tile[rr][rc + 8] = c.x;  tile[rr][rc + 9] = c.y;
        tile[rr][rc + 10] = c.z; tile[rr][rc + 11] = c.w;
        tile[rr][rc + 12] = d.x; tile[rr][rc + 13] = d.y;
        tile[rr][rc + 14] = d.z; tile[rr][rc + 15] = d.w;
        __syncthreads();
        // coalesced write: row (tn*64+rr) of Wt, 16 bf16 at k = tk*64+rc
        bf16x8 o0, o1;
#pragma unroll
        for (int j = 0; j < 8; j++) {
            o0[j] = (short)f2bf(C2LOG2E * tile[rc + j][rr]);
            o1[j] = (short)f2bf(C2LOG2E * tile[rc + 8 + j][rr]);
        }
        unsigned short* dst = Wt + (size_t)(tn * 64 + rr) * (3 * H) + tk * 64 + rc;
        *reinterpret_cast<bf16x8*>(dst) = o0;
        *reinterpret_cast<bf16x8*>(dst + 8) = o1;
    } else {
        int j = (blockIdx.x - nTr) * 256 + threadIdx.x;
        if (j >= n) return;
        int cur = seg_ids[j];
        int prev = (j == 0) ? -1 : seg_ids[j - 1];
        for (int s2 = prev + 1; s2 <= cur; s2++) seg_start[s2] = j;
        if (j == n - 1)
            for (int s2 = cur + 1; s2 <= num_seg; s2++) seg_start[s2] = n;
    }
}

// Merged tiled bf16 MFMA GEMM, tile 64(m) x 256(n), 4 waves (r12-exact).
// A staged via LDS; B (Wt rows, L2-hot) direct to registers.
// Blocks [0, nEntBlk): ent_proj  (out=comb stride 512; staged bf16 A also
//   written to comb em half).  Blocks [nEntBlk, ..): qpart (+bias).
__global__ void gemm_bf16_kernel(const float* __restrict__ entf,
                                 const int* __restrict__ sidx,
                                 const int* __restrict__ ridx,
                                 const float* __restrict__ rel,
                                 const unsigned short* __restrict__ Wt,
                                 const float* __restrict__ bias,
                                 unsigned short* __restrict__ comb,
                                 unsigned short* __restrict__ qpart,
                                 int nEntBlk, int M0, int M1) {
    __shared__ unsigned short As[64][40];
    bool isEnt = (int)blockIdx.x < nEntBlk;
    int m0 = (isEnt ? blockIdx.x : (blockIdx.x - nEntBlk)) * 64;
    int M = isEnt ? M0 : M1;
    int K = isEnt ? H : 2 * H;
    int k0 = isEnt ? 0 : H;
    int ldo = isEnt ? 512 : H;
    unsigned short* outp = isEnt ? comb : qpart;

    int t = threadIdx.x;
    int sr = t >> 2;          // 0..63
    int sc = (t & 3) * 8;     // 0/8/16/24
    int wave = t >> 6, lane = t & 63;
    int lr = lane & 15, lg = lane >> 4;

    f32x4 acc[4][4];
#pragma unroll
    for (int i = 0; i < 4; i++)
#pragma unroll
        for (int jn = 0; jn < 4; jn++) acc[i][jn] = (f32x4){0.f, 0.f, 0.f, 0.f};

    const unsigned short* bp[4];
#pragma unroll
    for (int bn = 0; bn < 4; bn++)
        bp[bn] = Wt + (size_t)(wave * 64 + bn * 16 + lr) * (3 * H) + k0 + lg * 8;

    for (int kk = 0; kk < K; kk += 32) {
        bf16x8 av = {};
        int gm = m0 + sr;
        if (gm < M) {
            const float* src;
            if (isEnt) {
                src = entf + (size_t)gm * H + kk + sc;
            } else {
                int k = kk + sc;
                src = (k < H) ? (entf + (size_t)sidx[gm] * H + k)
                              : (rel + (size_t)ridx[gm] * H + (k - H));
            }
            float4 f0 = *reinterpret_cast<const float4*>(src);
            float4 f1 = *reinterpret_cast<const float4*>(src + 4);
            av[0] = (short)f2bf(f0.x); av[1] = (short)f2bf(f0.y);
            av[2] = (short)f2bf(f0.z); av[3] = (short)f2bf(f0.w);
            av[4] = (short)f2bf(f1.x); av[5] = (short)f2bf(f1.y);
            av[6] = (short)f2bf(f1.z); av[7] = (short)f2bf(f1.w);
            if (isEnt)
                *reinterpret_cast<bf16x8*>(comb + (size_t)gm * 512 + 256 + kk + sc) = av;
        }
        *reinterpret_cast<bf16x8*>(&As[sr][sc]) = av;

        bf16x8 bfr[4];
#pragma unroll
        for (int bn = 0; bn < 4; bn++)
            bfr[bn] = *reinterpret_cast<const bf16x8*>(bp[bn] + kk);

        __syncthreads();
        bf16x8 afr[4];
#pragma unroll
        for (int am = 0; am < 4; am++)
            afr[am] = *reinterpret_cast<const bf16x8*>(&As[am * 16 + lr][lg * 8]);
#pragma unroll
        for (int am = 0; am < 4; am++)
#pragma unroll
            for (int bn = 0; bn < 4; bn++)
                acc[am][bn] = __builtin_amdgcn_mfma_f32_16x16x32_bf16(
                    afr[am], bfr[bn], acc[am][bn], 0, 0, 0);
        __syncthreads();
    }

#pragma unroll
    for (int bn = 0; bn < 4; bn++) {
        int col = wave * 64 + bn * 16 + lr;
        float bv = isEnt ? 0.f : C2LOG2E * bias[col];
#pragma unroll
        for (int am = 0; am < 4; am++) {
#pragma unroll
            for (int rr = 0; rr < 4; rr++) {
                int row = m0 + am * 16 + lg * 4 + rr;
                if (row < M)
                    outp[(size_t)row * ldo + col] = f2bf(acc[am][bn][rr] + bv);
            }
        }
    }
}

// One wave per segment, 2 waves per block (r12-exact body, best measured:
// fused 57.2us). Lane group g (16 lanes) handles neighbors j == 4*ji+g; lane
// covers 16 cols. Single pass, no max-subtraction (|score| <= ~10.2).
// proj & qpart pre-scaled by 2*log2e. Paired-rcp score (exact algebra):
//   v0/(u0+1) + v1/(u1+1) = (v0*a1 + v1*a0) * rcp(a0*a1)   [a=u+1]
// Deltas vs r12 (isolated, low-risk):
//   - 2-deep nbr-index pipeline: index load for iter ji+2 issued at iter ji,
//     so the nbr_ids -> comb-row dependent chain is overlapped (+1 VGPR).
//   - butterfly cross-group combine (12 shfl vs 32; verified r14-r16).
// VGPR must stay <= 64 (cliff measured r14/r15: >64 costs ~35%).
__global__ void __launch_bounds__(128)
fused_agg_kernel(const int* __restrict__ nbr_ids,
                 const int* __restrict__ seg_start,
                 const unsigned short* __restrict__ comb,
                 const unsigned short* __restrict__ qpartbf,
                 const float* __restrict__ v_s,
                 const float* __restrict__ ent_embeds,
                 const float* __restrict__ rel_embeds,
                 const int* __restrict__ s,
                 const int* __restrict__ r,
                 float* __restrict__ out, int num_seg) {
    int seg = blockIdx.x * 2 + (threadIdx.x >> 6);
    if (seg >= num_seg) return;
    int lane = threadIdx.x & 63;
    int g = lane >> 4, li = lane & 15;
    int cb = li * 16;
    int c4 = lane * 4;
    int b = seg / SEQ;
    int start = seg_start[seg], end = seg_start[seg + 1];
    float* orow = out + (size_t)seg * (3 * H);

    if (start == end) {
        float4 z = {0.f, 0.f, 0.f, 0.f};
        *reinterpret_cast<float4*>(orow + c4) = z;
        *reinterpret_cast<float4*>(orow + H + c4) = z;
        *reinterpret_cast<float4*>(orow + 2 * H + c4) = z;
        return;
    }

    // issue ss/rr gathers early — consumed only at the end
    float4 ssv = *reinterpret_cast<const float4*>(ent_embeds + (size_t)s[b] * H + c4);
    float4 rrv = *reinterpret_cast<const float4*>(rel_embeds + (size_t)r[b] * H + c4);

    // v columns for this lane
    float vm2[16];  // -2*v
    float vsum = 0.f;
    {
        const float4* vp = reinterpret_cast<const float4*>(v_s + cb);
#pragma unroll
        for (int k = 0; k < 4; k++) {
            float4 tv = vp[k];
            vm2[4 * k + 0] = -2.f * tv.x; vm2[4 * k + 1] = -2.f * tv.y;
            vm2[4 * k + 2] = -2.f * tv.z; vm2[4 * k + 3] = -2.f * tv.w;
            vsum += tv.x + tv.y + tv.z + tv.w;
        }
    }

    float qv[16];
    {
        bf16x8 qa = *reinterpret_cast<const bf16x8*>(qpartbf + (size_t)b * H + cb);
        bf16x8 qb = *reinterpret_cast<const bf16x8*>(qpartbf + (size_t)b * H + cb + 8);
#pragma unroll
        for (int k = 0; k < 8; k++) {
            qv[k] = bf2f((unsigned short)qa[k]);
            qv[8 + k] = bf2f((unsigned short)qb[k]);
        }
    }

    float acc[16];
#pragma unroll
    for (int k = 0; k < 16; k++) acc[k] = 0.f;
    float lpart = 0.f;

    int cc = end - start;
    int nitm = (cc + 3) >> 2;

    // 2-deep index pipeline: nbB holds the row index for the NEXT iteration's
    // row prefetch (clamped index loads are cheap; row gathers stay predicated)
    int nbA = nbr_ids[start + min(g, cc - 1)];
    int nbB = nbr_ids[start + min(4 + g, cc - 1)];

    // prologue: predicated load of row j=g (proj + em)
    bf16x8 p0 = {}, p1 = {}, e0 = {}, e1 = {};
    if (g < cc) {
        const unsigned short* row = comb + (size_t)nbA * 512 + cb;
        p0 = *reinterpret_cast<const bf16x8*>(row);
        p1 = *reinterpret_cast<const bf16x8*>(row + 8);
        e0 = *reinterpret_cast<const bf16x8*>(row + 256);
        e1 = *reinterpret_cast<const bf16x8*>(row + 264);
    }

    for (int ji = 0; ji < nitm; ji++) {
        // predicated prefetch of next row (proj + em), index already resolved
        bf16x8 p0n = {}, p1n = {}, e0n = {}, e1n = {};
        int jn = 4 * (ji + 1) + g;
        if (jn < cc) {
            const unsigned short* rown = comb + (size_t)nbB * 512 + cb;
            p0n = *reinterpret_cast<const bf16x8*>(rown);
            p1n = *reinterpret_cast<const bf16x8*>(rown + 8);
            e0n = *reinterpret_cast<const bf16x8*>(rown + 256);
            e1n = *reinterpret_cast<const bf16x8*>(rown + 264);
        }
        // resolve the index for iteration ji+2 (full iteration of cover)
        int nbC = nbr_ids[start + min(4 * (ji + 2) + g, cc - 1)];

        // paired-rcp score: 2 exp2 + 1 rcp per element pair
        float sa = 0.f, sb = 0.f;
#pragma unroll
        for (int k = 0; k < 8; k += 2) {
            float a0 = fexp2(bf2f((unsigned short)p0[k]) + qv[k]) + 1.f;
            float a1 = fexp2(bf2f((unsigned short)p1[k]) + qv[8 + k]) + 1.f;
            float num = vm2[k] * a1;
            num = fmaf(vm2[8 + k], a0, num);
            sa = fmaf(num, __builtin_amdgcn_rcpf(a0 * a1), sa);
            float b0 = fexp2(bf2f((unsigned short)p0[k + 1]) + qv[k + 1]) + 1.f;
            float b1 = fexp2(bf2f((unsigned short)p1[k + 1]) + qv[9 + k]) + 1.f;
            float numb = vm2[k + 1] * b1;
            numb = fmaf(vm2[9 + k], b0, numb);
            sb = fmaf(numb, __builtin_amdgcn_rcpf(b0 * b1), sb);
        }
        float s16 = sa + sb + vsum;
        s16 += __shfl_xor(s16, 1);
        s16 += __shfl_xor(s16, 2);
        s16 += __shfl_xor(s16, 4);
        s16 += __shfl_xor(s16, 8);
        float e = fexp2(s16 * LOG2E);
        e = (4 * ji + g < cc) ? e : 0.f;
        lpart += e;
#pragma unroll
        for (int k = 0; k < 8; k++) {
            acc[k] = fmaf(e, bf2f((unsigned short)e0[k]), acc[k]);
            acc[8 + k] = fmaf(e, bf2f((unsigned short)e1[k]), acc[8 + k]);
        }
        p0 = p0n; p1 = p1n; e0 = e0n; e1 = e1n;
        nbB = nbC;
    }

    // lpart combine (all 64 lanes hold partials)
    lpart += __shfl_xor(lpart, 16);
    lpart += __shfl_xor(lpart, 32);
    float invl = 1.f / lpart;

    // register-halving butterfly: lane in group g ends with acc[4g..4g+3]
    int gb0 = g & 1, gb1 = g >> 1;
    float t1[8];
#pragma unroll
    for (int j = 0; j < 8; j++) {
        int sl0 = (j < 4) ? j : 4 + j;       // L0 = {0,1,2,3,8,9,10,11}
        int sl1 = sl0 + 4;                   // L1 = {4,5,6,7,12,13,14,15}
        float mine = gb0 ? acc[sl1] : acc[sl0];
        float opp  = gb0 ? acc[sl0] : acc[sl1];
        t1[j] = mine + __shfl_xor(opp, 16);
    }
    float4 o;
#pragma unroll
    for (int j = 0; j < 4; j++) {
        float mine = gb1 ? t1[4 + j] : t1[j];
        float opp  = gb1 ? t1[j] : t1[4 + j];
        float fin = (mine + __shfl_xor(opp, 32)) * invl;
        if (j == 0) o.x = fin;
        else if (j == 1) o.y = fin;
        else if (j == 2) o.z = fin;
        else o.w = fin;
    }
    *reinterpret_cast<float4*>(orow + cb + 4 * g) = o;
    *reinterpret_cast<float4*>(orow + H + c4) = ssv;
    *reinterpret_cast<float4*>(orow + 2 * H + c4) = rrv;
}

extern "C" void kernel_launch(void* const* d_in, const int* in_sizes, int n_in,
                              void* d_out, int out_size, void* d_ws, size_t ws_size,
                              hipStream_t stream) {
    const int* s = (const int*)d_in[0];
    const int* r = (const int*)d_in[1];
    const int* nbr_ids = (const int*)d_in[2];
    const int* seg_ids = (const int*)d_in[3];
    const float* ent_embeds = (const float*)d_in[4];
    const float* rel_embeds = (const float*)d_in[5];
    const float* W_attn = (const float*)d_in[6];
    const float* b_attn = (const float*)d_in[7];
    const float* v_s = (const float*)d_in[8];
    float* out = (float*)d_out;

    int B = in_sizes[0];
    int N = in_sizes[2];
    int num_ent = in_sizes[4] / H;
    int num_seg = B * SEQ;

    char* ws = (char*)d_ws;
    unsigned short* comb = (unsigned short*)ws;                 // num_ent*512 (proj'|em)
    unsigned short* Wt = comb + (size_t)num_ent * 512;          // H*3H (pre-scaled)
    unsigned short* qpartbf = Wt + (size_t)H * 3 * H;           // B*H (pre-scaled)
    int* seg_start = (int*)(qpartbf + (size_t)B * H);           // num_seg+1

    int nTr = 12 * 4;                        // 48 transpose tiles
    int nSeg = (N + 255) / 256;              // 1280
    prep_kernel<<<nTr + nSeg, 256, 0, stream>>>(W_attn, Wt, seg_ids, seg_start,
                                                nTr, N, num_seg);

    int nEntBlk = (num_ent + 63) / 64;       // 313
    int nQBlk = B / 64;                      // 32
    gemm_bf16_kernel<<<nEntBlk + nQBlk, 256, 0, stream>>>(
        ent_embeds, s, r, rel_embeds, Wt, b_attn, comb, qpartbf,
        nEntBlk, num_ent, B);

    fused_agg_kernel<<<(num_seg + 1) / 2, 128, 0, stream>>>(
        nbr_ids, seg_start, comb, qpartbf, v_s,
        ent_embeds, rel_embeds, s, r, out, num_seg);
}

// Round 18
// 91.112 us; speedup vs baseline: 1.2058x; 1.0766x over previous
//
#include <hip/hip_runtime.h>
#include <hip/hip_bf16.h>

#define H 256
#define SEQ 10
#define C2LOG2E 2.8853900817779268f   // 2*log2(e)
#define LOG2E 1.4426950408889634f

typedef __attribute__((ext_vector_type(8))) short bf16x8;
typedef __attribute__((ext_vector_type(4))) float f32x4;

__device__ __forceinline__ unsigned short f2bf(float x) {
    union { float f; unsigned u; } v; v.f = x;
    unsigned r = v.u + 0x7fff + ((v.u >> 16) & 1);  // RNE
    return (unsigned short)(r >> 16);
}
__device__ __forceinline__ float bf2f(unsigned short b) {
    union { unsigned u; float f; } v; v.u = ((unsigned)b) << 16;
    return v.f;
}
__device__ __forceinline__ float fexp2(float x) {
    return __builtin_amdgcn_exp2f(x);
}

// prep: blocks [0, nTr) build Wt via LDS tile transpose (coalesced read AND
// write — measured ~2.5us faster than the scalar strided version).
// Wt[n][k] = bf16(2log2e * W[k][n]), row-major [H][3H].
// Blocks [nTr, ...) build seg_start.
__global__ void prep_kernel(const float* __restrict__ W,
                            unsigned short* __restrict__ Wt,
                            const int* __restrict__ seg_ids,
                            int* __restrict__ seg_start,
                            int nTr, int n, int num_seg) {
    if ((int)blockIdx.x < nTr) {
        __shared__ float tile[64][65];
        int tk = blockIdx.x % 12;   // k-tile (3H/64 = 12)
        int tn = blockIdx.x / 12;   // n-tile (H/64 = 4)
        int t = threadIdx.x;
        int rr = t >> 2;            // 0..63
        int rc = (t & 3) * 16;      // 0,16,32,48
        const float* src = W + (size_t)(tk * 64 + rr) * H + tn * 64 + rc;
        float4 a = *reinterpret_cast<const float4*>(src);
        float4 b = *reinterpret_cast<const float4*>(src + 4);
        float4 c = *reinterpret_cast<const float4*>(src + 8);
        float4 d = *reinterpret_cast<const float4*>(src + 12);
        tile[rr][rc + 0] = a.x;  tile[rr][rc + 1] = a.y;
        tile[rr][rc + 2] = a.z;  tile[rr][rc + 3] = a.w;
        tile[rr][rc + 4] = b.x;  tile[rr][rc + 5] = b.y;
        tile[rr][rc + 6] = b.z;  tile[rr][rc + 7] = b.w;
        tile[rr][rc + 8] = c.x;  tile[rr][rc + 9] = c.y;
        tile[rr][rc + 10] = c.z; tile[rr][rc + 11] = c.w;
        tile[rr][rc + 12] = d.x; tile[rr][rc + 13] = d.y;
        tile[rr][rc + 14] = d.z; tile[rr][rc + 15] = d.w;
        __syncthreads();
        bf16x8 o0, o1;
#pragma unroll
        for (int j = 0; j < 8; j++) {
            o0[j] = (short)f2bf(C2LOG2E * tile[rc + j][rr]);
            o1[j] = (short)f2bf(C2LOG2E * tile[rc + 8 + j][rr]);
        }
        unsigned short* dst = Wt + (size_t)(tn * 64 + rr) * (3 * H) + tk * 64 + rc;
        *reinterpret_cast<bf16x8*>(dst) = o0;
        *reinterpret_cast<bf16x8*>(dst + 8) = o1;
    } else {
        int j = (blockIdx.x - nTr) * 256 + threadIdx.x;
        if (j >= n) return;
        int cur = seg_ids[j];
        int prev = (j == 0) ? -1 : seg_ids[j - 1];
        for (int s2 = prev + 1; s2 <= cur; s2++) seg_start[s2] = j;
        if (j == n - 1)
            for (int s2 = cur + 1; s2 <= num_seg; s2++) seg_start[s2] = n;
    }
}

// Merged tiled bf16 MFMA GEMM, tile 64(m) x 256(n), 4 waves (r12-exact).
// A staged via LDS; B (Wt rows, L2-hot) direct to registers.
// Blocks [0, nEntBlk): ent_proj  (out=comb stride 512; staged bf16 A also
//   written to comb em half).  Blocks [nEntBlk, ..): qpart (+bias).
__global__ void gemm_bf16_kernel(const float* __restrict__ entf,
                                 const int* __restrict__ sidx,
                                 const int* __restrict__ ridx,
                                 const float* __restrict__ rel,
                                 const unsigned short* __restrict__ Wt,
                                 const float* __restrict__ bias,
                                 unsigned short* __restrict__ comb,
                                 unsigned short* __restrict__ qpart,
                                 int nEntBlk, int M0, int M1) {
    __shared__ unsigned short As[64][40];
    bool isEnt = (int)blockIdx.x < nEntBlk;
    int m0 = (isEnt ? blockIdx.x : (blockIdx.x - nEntBlk)) * 64;
    int M = isEnt ? M0 : M1;
    int K = isEnt ? H : 2 * H;
    int k0 = isEnt ? 0 : H;
    int ldo = isEnt ? 512 : H;
    unsigned short* outp = isEnt ? comb : qpart;

    int t = threadIdx.x;
    int sr = t >> 2;          // 0..63
    int sc = (t & 3) * 8;     // 0/8/16/24
    int wave = t >> 6, lane = t & 63;
    int lr = lane & 15, lg = lane >> 4;

    f32x4 acc[4][4];
#pragma unroll
    for (int i = 0; i < 4; i++)
#pragma unroll
        for (int jn = 0; jn < 4; jn++) acc[i][jn] = (f32x4){0.f, 0.f, 0.f, 0.f};

    const unsigned short* bp[4];
#pragma unroll
    for (int bn = 0; bn < 4; bn++)
        bp[bn] = Wt + (size_t)(wave * 64 + bn * 16 + lr) * (3 * H) + k0 + lg * 8;

    for (int kk = 0; kk < K; kk += 32) {
        bf16x8 av = {};
        int gm = m0 + sr;
        if (gm < M) {
            const float* src;
            if (isEnt) {
                src = entf + (size_t)gm * H + kk + sc;
            } else {
                int k = kk + sc;
                src = (k < H) ? (entf + (size_t)sidx[gm] * H + k)
                              : (rel + (size_t)ridx[gm] * H + (k - H));
            }
            float4 f0 = *reinterpret_cast<const float4*>(src);
            float4 f1 = *reinterpret_cast<const float4*>(src + 4);
            av[0] = (short)f2bf(f0.x); av[1] = (short)f2bf(f0.y);
            av[2] = (short)f2bf(f0.z); av[3] = (short)f2bf(f0.w);
            av[4] = (short)f2bf(f1.x); av[5] = (short)f2bf(f1.y);
            av[6] = (short)f2bf(f1.z); av[7] = (short)f2bf(f1.w);
            if (isEnt)
                *reinterpret_cast<bf16x8*>(comb + (size_t)gm * 512 + 256 + kk + sc) = av;
        }
        *reinterpret_cast<bf16x8*>(&As[sr][sc]) = av;

        bf16x8 bfr[4];
#pragma unroll
        for (int bn = 0; bn < 4; bn++)
            bfr[bn] = *reinterpret_cast<const bf16x8*>(bp[bn] + kk);

        __syncthreads();
        bf16x8 afr[4];
#pragma unroll
        for (int am = 0; am < 4; am++)
            afr[am] = *reinterpret_cast<const bf16x8*>(&As[am * 16 + lr][lg * 8]);
#pragma unroll
        for (int am = 0; am < 4; am++)
#pragma unroll
            for (int bn = 0; bn < 4; bn++)
                acc[am][bn] = __builtin_amdgcn_mfma_f32_16x16x32_bf16(
                    afr[am], bfr[bn], acc[am][bn], 0, 0, 0);
        __syncthreads();
    }

#pragma unroll
    for (int bn = 0; bn < 4; bn++) {
        int col = wave * 64 + bn * 16 + lr;
        float bv = isEnt ? 0.f : C2LOG2E * bias[col];
#pragma unroll
        for (int am = 0; am < 4; am++) {
#pragma unroll
            for (int rr = 0; rr < 4; rr++) {
                int row = m0 + am * 16 + lg * 4 + rr;
                if (row < M)
                    outp[(size_t)row * ldo + col] = f2bf(acc[am][bn][rr] + bv);
            }
        }
    }
}

// One wave per segment, 2 waves per block — r12-EXACT body (best measured:
// fused 57.2us, total 91.2us). Lane group g (16 lanes) handles neighbors
// j == 4*ji+g; lane covers 16 cols. Single pass, no max-subtraction
// (|score| <= ~10.2). proj & qpart pre-scaled by 2*log2e. Paired-rcp score:
//   v0/(u0+1) + v1/(u1+1) = (v0*a1 + v1*a0) * rcp(a0*a1)   [a=u+1]
// Gathers exec-predicated; proj+em prefetched 1-deep; ss/rr issued early.
// PLAIN 32-shfl cross-group combine — the butterfly variant measured +9.5us
// in every round that carried it (r14-r17); do not reintroduce.
// VGPR must stay <= 64 (cliff measured r14/r15: >64 costs ~35%).
__global__ void __launch_bounds__(128)
fused_agg_kernel(const int* __restrict__ nbr_ids,
                 const int* __restrict__ seg_start,
                 const unsigned short* __restrict__ comb,
                 const unsigned short* __restrict__ qpartbf,
                 const float* __restrict__ v_s,
                 const float* __restrict__ ent_embeds,
                 const float* __restrict__ rel_embeds,
                 const int* __restrict__ s,
                 const int* __restrict__ r,
                 float* __restrict__ out, int num_seg) {
    int seg = blockIdx.x * 2 + (threadIdx.x >> 6);
    if (seg >= num_seg) return;
    int lane = threadIdx.x & 63;
    int g = lane >> 4, li = lane & 15;
    int cb = li * 16;
    int c4 = lane * 4;
    int b = seg / SEQ;
    int start = seg_start[seg], end = seg_start[seg + 1];
    float* orow = out + (size_t)seg * (3 * H);

    if (start == end) {
        float4 z = {0.f, 0.f, 0.f, 0.f};
        *reinterpret_cast<float4*>(orow + c4) = z;
        *reinterpret_cast<float4*>(orow + H + c4) = z;
        *reinterpret_cast<float4*>(orow + 2 * H + c4) = z;
        return;
    }

    // issue ss/rr gathers early — consumed only at the end
    float4 ssv = *reinterpret_cast<const float4*>(ent_embeds + (size_t)s[b] * H + c4);
    float4 rrv = *reinterpret_cast<const float4*>(rel_embeds + (size_t)r[b] * H + c4);

    // v columns for this lane
    float vm2[16];  // -2*v
    float vsum = 0.f;
    {
        const float4* vp = reinterpret_cast<const float4*>(v_s + cb);
#pragma unroll
        for (int k = 0; k < 4; k++) {
            float4 tv = vp[k];
            vm2[4 * k + 0] = -2.f * tv.x; vm2[4 * k + 1] = -2.f * tv.y;
            vm2[4 * k + 2] = -2.f * tv.z; vm2[4 * k + 3] = -2.f * tv.w;
            vsum += tv.x + tv.y + tv.z + tv.w;
        }
    }

    float qv[16];
    {
        bf16x8 qa = *reinterpret_cast<const bf16x8*>(qpartbf + (size_t)b * H + cb);
        bf16x8 qb = *reinterpret_cast<const bf16x8*>(qpartbf + (size_t)b * H + cb + 8);
#pragma unroll
        for (int k = 0; k < 8; k++) {
            qv[k] = bf2f((unsigned short)qa[k]);
            qv[8 + k] = bf2f((unsigned short)qb[k]);
        }
    }

    float acc[16];
#pragma unroll
    for (int k = 0; k < 16; k++) acc[k] = 0.f;
    float lpart = 0.f;

    int cc = end - start;
    int nitm = (cc + 3) >> 2;

    // prologue: predicated load of row j=g (proj + em)
    bf16x8 p0 = {}, p1 = {}, e0 = {}, e1 = {};
    if (g < cc) {
        const unsigned short* row = comb + (size_t)nbr_ids[start + g] * 512 + cb;
        p0 = *reinterpret_cast<const bf16x8*>(row);
        p1 = *reinterpret_cast<const bf16x8*>(row + 8);
        e0 = *reinterpret_cast<const bf16x8*>(row + 256);
        e1 = *reinterpret_cast<const bf16x8*>(row + 264);
    }

    for (int ji = 0; ji < nitm; ji++) {
        // predicated prefetch of next row (proj + em)
        bf16x8 p0n = {}, p1n = {}, e0n = {}, e1n = {};
        int jn = 4 * (ji + 1) + g;
        if (jn < cc) {
            const unsigned short* rown = comb + (size_t)nbr_ids[start + jn] * 512 + cb;
            p0n = *reinterpret_cast<const bf16x8*>(rown);
            p1n = *reinterpret_cast<const bf16x8*>(rown + 8);
            e0n = *reinterpret_cast<const bf16x8*>(rown + 256);
            e1n = *reinterpret_cast<const bf16x8*>(rown + 264);
        }

        // paired-rcp score: 2 exp2 + 1 rcp per element pair
        float sa = 0.f, sb = 0.f;
#pragma unroll
        for (int k = 0; k < 8; k += 2) {
            float a0 = fexp2(bf2f((unsigned short)p0[k]) + qv[k]) + 1.f;
            float a1 = fexp2(bf2f((unsigned short)p1[k]) + qv[8 + k]) + 1.f;
            float num = vm2[k] * a1;
            num = fmaf(vm2[8 + k], a0, num);
            sa = fmaf(num, __builtin_amdgcn_rcpf(a0 * a1), sa);
            float b0 = fexp2(bf2f((unsigned short)p0[k + 1]) + qv[k + 1]) + 1.f;
            float b1 = fexp2(bf2f((unsigned short)p1[k + 1]) + qv[9 + k]) + 1.f;
            float numb = vm2[k + 1] * b1;
            numb = fmaf(vm2[9 + k], b0, numb);
            sb = fmaf(numb, __builtin_amdgcn_rcpf(b0 * b1), sb);
        }
        float s16 = sa + sb + vsum;
        s16 += __shfl_xor(s16, 1);
        s16 += __shfl_xor(s16, 2);
        s16 += __shfl_xor(s16, 4);
        s16 += __shfl_xor(s16, 8);
        float e = fexp2(s16 * LOG2E);
        e = (4 * ji + g < cc) ? e : 0.f;
        lpart += e;
#pragma unroll
        for (int k = 0; k < 8; k++) {
            acc[k] = fmaf(e, bf2f((unsigned short)e0[k]), acc[k]);
            acc[8 + k] = fmaf(e, bf2f((unsigned short)e1[k]), acc[8 + k]);
        }
        p0 = p0n; p1 = p1n; e0 = e0n; e1 = e1n;
    }

    // combine the 4 lane-groups (plain shfl — fastest measured)
    lpart += __shfl_xor(lpart, 16);
    lpart += __shfl_xor(lpart, 32);
#pragma unroll
    for (int k = 0; k < 16; k++) {
        acc[k] += __shfl_xor(acc[k], 16);
        acc[k] += __shfl_xor(acc[k], 32);
    }
    float invl = 1.f / lpart;

    // lane (g,li) writes cols cb + 4g .. cb+4g+3 (static selects)
    float4 o;
#pragma unroll
    for (int k = 0; k < 4; k++) {
        float v0 = acc[k], v1 = acc[4 + k], v2 = acc[8 + k], v3 = acc[12 + k];
        float pick = (g == 0) ? v0 : (g == 1) ? v1 : (g == 2) ? v2 : v3;
        if (k == 0) o.x = pick * invl;
        else if (k == 1) o.y = pick * invl;
        else if (k == 2) o.z = pick * invl;
        else o.w = pick * invl;
    }
    *reinterpret_cast<float4*>(orow + cb + 4 * g) = o;
    *reinterpret_cast<float4*>(orow + H + c4) = ssv;
    *reinterpret_cast<float4*>(orow + 2 * H + c4) = rrv;
}

extern "C" void kernel_launch(void* const* d_in, const int* in_sizes, int n_in,
                              void* d_out, int out_size, void* d_ws, size_t ws_size,
                              hipStream_t stream) {
    const int* s = (const int*)d_in[0];
    const int* r = (const int*)d_in[1];
    const int* nbr_ids = (const int*)d_in[2];
    const int* seg_ids = (const int*)d_in[3];
    const float* ent_embeds = (const float*)d_in[4];
    const float* rel_embeds = (const float*)d_in[5];
    const float* W_attn = (const float*)d_in[6];
    const float* b_attn = (const float*)d_in[7];
    const float* v_s = (const float*)d_in[8];
    float* out = (float*)d_out;

    int B = in_sizes[0];
    int N = in_sizes[2];
    int num_ent = in_sizes[4] / H;
    int num_seg = B * SEQ;

    char* ws = (char*)d_ws;
    unsigned short* comb = (unsigned short*)ws;                 // num_ent*512 (proj'|em)
    unsigned short* Wt = comb + (size_t)num_ent * 512;          // H*3H (pre-scaled)
    unsigned short* qpartbf = Wt + (size_t)H * 3 * H;           // B*H (pre-scaled)
    int* seg_start = (int*)(qpartbf + (size_t)B * H);           // num_seg+1

    int nTr = 12 * 4;                        // 48 transpose tiles
    int nSeg = (N + 255) / 256;              // 1280
    prep_kernel<<<nTr + nSeg, 256, 0, stream>>>(W_attn, Wt, seg_ids, seg_start,
                                                nTr, N, num_seg);

    int nEntBlk = (num_ent + 63) / 64;       // 313
    int nQBlk = B / 64;                      // 32
    gemm_bf16_kernel<<<nEntBlk + nQBlk, 256, 0, stream>>>(
        ent_embeds, s, r, rel_embeds, Wt, b_attn, comb, qpartbf,
        nEntBlk, num_ent, B);

    fused_agg_kernel<<<(num_seg + 1) / 2, 128, 0, stream>>>(
        nbr_ids, seg_start, comb, qpartbf, v_s,
        ent_embeds, rel_embeds, s, r, out, num_seg);
}

// Round 19
// 89.156 us; speedup vs baseline: 1.2323x; 1.0219x over previous
//
#include <hip/hip_runtime.h>
#include <hip/hip_bf16.h>

#define H 256
#define SEQ 10
#define C2LOG2E 2.8853900817779268f   // 2*log2(e)
#define LOG2E 1.4426950408889634f

typedef __attribute__((ext_vector_type(8))) short bf16x8;
typedef __attribute__((ext_vector_type(4))) float f32x4;

__device__ __forceinline__ unsigned short f2bf(float x) {
    union { float f; unsigned u; } v; v.f = x;
    unsigned r = v.u + 0x7fff + ((v.u >> 16) & 1);  // RNE
    return (unsigned short)(r >> 16);
}
__device__ __forceinline__ float bf2f(unsigned short b) {
    union { unsigned u; float f; } v; v.u = ((unsigned)b) << 16;
    return v.f;
}
__device__ __forceinline__ float fexp2(float x) {
    return __builtin_amdgcn_exp2f(x);
}

// prep: 48 blocks, Wt via LDS tile transpose (coalesced both sides).
// Wt[n][k] = bf16(2log2e * W[k][n]), row-major [H][3H].
__global__ void prep_kernel(const float* __restrict__ W,
                            unsigned short* __restrict__ Wt) {
    __shared__ float tile[64][65];
    int tk = blockIdx.x % 12;   // k-tile (3H/64 = 12)
    int tn = blockIdx.x / 12;   // n-tile (H/64 = 4)
    int t = threadIdx.x;
    int rr = t >> 2;            // 0..63
    int rc = (t & 3) * 16;      // 0,16,32,48
    const float* src = W + (size_t)(tk * 64 + rr) * H + tn * 64 + rc;
    float4 a = *reinterpret_cast<const float4*>(src);
    float4 b = *reinterpret_cast<const float4*>(src + 4);
    float4 c = *reinterpret_cast<const float4*>(src + 8);
    float4 d = *reinterpret_cast<const float4*>(src + 12);
    tile[rr][rc + 0] = a.x;  tile[rr][rc + 1] = a.y;
    tile[rr][rc + 2] = a.z;  tile[rr][rc + 3] = a.w;
    tile[rr][rc + 4] = b.x;  tile[rr][rc + 5] = b.y;
    tile[rr][rc + 6] = b.z;  tile[rr][rc + 7] = b.w;
    tile[rr][rc + 8] = c.x;  tile[rr][rc + 9] = c.y;
    tile[rr][rc + 10] = c.z; tile[rr][rc + 11] = c.w;
    tile[rr][rc + 12] = d.x; tile[rr][rc + 13] = d.y;
    tile[rr][rc + 14] = d.z; tile[rr][rc + 15] = d.w;
    __syncthreads();
    bf16x8 o0, o1;
#pragma unroll
    for (int j = 0; j < 8; j++) {
        o0[j] = (short)f2bf(C2LOG2E * tile[rc + j][rr]);
        o1[j] = (short)f2bf(C2LOG2E * tile[rc + 8 + j][rr]);
    }
    unsigned short* dst = Wt + (size_t)(tn * 64 + rr) * (3 * H) + tk * 64 + rc;
    *reinterpret_cast<bf16x8*>(dst) = o0;
    *reinterpret_cast<bf16x8*>(dst + 8) = o1;
}

// Merged launch: GEMM blocks + seg_start rider blocks (independent of Wt,
// overlap the GEMM). GEMM: tile 32(m) x 256(n), BK=64, 4 waves — 625 ent +
// 64 qpart blocks (2.7/CU vs 1.35 at M=64: halves the tail quantum; exact
// division, no tail rows). A staged via LDS; B (Wt, L2-hot) direct to regs.
// ent blocks: out=comb stride 512; staged bf16 A also written to comb em
// half. qpart blocks: A row m = [ent[s[m]]|rel[r[m]]], K=512, k0=H, +bias.
__global__ void gemm_bf16_kernel(const float* __restrict__ entf,
                                 const int* __restrict__ sidx,
                                 const int* __restrict__ ridx,
                                 const float* __restrict__ rel,
                                 const unsigned short* __restrict__ Wt,
                                 const float* __restrict__ bias,
                                 unsigned short* __restrict__ comb,
                                 unsigned short* __restrict__ qpart,
                                 const int* __restrict__ seg_ids,
                                 int* __restrict__ seg_start,
                                 int n, int num_seg,
                                 int nEntBlk, int nQBlk, int M0, int M1) {
    __shared__ unsigned short As[32][72];   // 64 k + 8 pad (144B rows, 16B-aligned)
    int bid = blockIdx.x;
    if (bid >= nEntBlk + nQBlk) {
        // seg_start rider blocks
        int j = (bid - nEntBlk - nQBlk) * 256 + threadIdx.x;
        if (j >= n) return;
        int cur = seg_ids[j];
        int prev = (j == 0) ? -1 : seg_ids[j - 1];
        for (int s2 = prev + 1; s2 <= cur; s2++) seg_start[s2] = j;
        if (j == n - 1)
            for (int s2 = cur + 1; s2 <= num_seg; s2++) seg_start[s2] = n;
        return;
    }

    bool isEnt = bid < nEntBlk;
    int m0 = (isEnt ? bid : (bid - nEntBlk)) * 32;
    int M = isEnt ? M0 : M1;
    int K = isEnt ? H : 2 * H;
    int k0 = isEnt ? 0 : H;
    int ldo = isEnt ? 512 : H;
    unsigned short* outp = isEnt ? comb : qpart;

    int t = threadIdx.x;
    int sr = t >> 3;          // staging row 0..31
    int sc = (t & 7) * 8;     // staging k-offset 0,8,..56
    int wave = t >> 6, lane = t & 63;
    int lr = lane & 15, lg = lane >> 4;

    f32x4 acc[2][4];
#pragma unroll
    for (int i = 0; i < 2; i++)
#pragma unroll
        for (int jn = 0; jn < 4; jn++) acc[i][jn] = (f32x4){0.f, 0.f, 0.f, 0.f};

    const unsigned short* bp[4];
#pragma unroll
    for (int bn = 0; bn < 4; bn++)
        bp[bn] = Wt + (size_t)(wave * 64 + bn * 16 + lr) * (3 * H) + k0 + lg * 8;

    for (int kk = 0; kk < K; kk += 64) {
        bf16x8 av = {};
        int gm = m0 + sr;
        if (gm < M) {
            const float* src;
            if (isEnt) {
                src = entf + (size_t)gm * H + kk + sc;
            } else {
                int k = kk + sc;
                src = (k < H) ? (entf + (size_t)sidx[gm] * H + k)
                              : (rel + (size_t)ridx[gm] * H + (k - H));
            }
            float4 f0 = *reinterpret_cast<const float4*>(src);
            float4 f1 = *reinterpret_cast<const float4*>(src + 4);
            av[0] = (short)f2bf(f0.x); av[1] = (short)f2bf(f0.y);
            av[2] = (short)f2bf(f0.z); av[3] = (short)f2bf(f0.w);
            av[4] = (short)f2bf(f1.x); av[5] = (short)f2bf(f1.y);
            av[6] = (short)f2bf(f1.z); av[7] = (short)f2bf(f1.w);
            if (isEnt)
                *reinterpret_cast<bf16x8*>(comb + (size_t)gm * 512 + 256 + kk + sc) = av;
        }
        *reinterpret_cast<bf16x8*>(&As[sr][sc]) = av;

        // B fragments direct from global (L2-hot): 2 k-halves x 4 col-frags
        bf16x8 bfr[2][4];
#pragma unroll
        for (int kh = 0; kh < 2; kh++)
#pragma unroll
            for (int bn = 0; bn < 4; bn++)
                bfr[kh][bn] = *reinterpret_cast<const bf16x8*>(bp[bn] + kk + kh * 32);

        __syncthreads();
#pragma unroll
        for (int kh = 0; kh < 2; kh++) {
            bf16x8 afr[2];
#pragma unroll
            for (int am = 0; am < 2; am++)
                afr[am] = *reinterpret_cast<const bf16x8*>(&As[am * 16 + lr][kh * 32 + lg * 8]);
#pragma unroll
            for (int am = 0; am < 2; am++)
#pragma unroll
                for (int bn = 0; bn < 4; bn++)
                    acc[am][bn] = __builtin_amdgcn_mfma_f32_16x16x32_bf16(
                        afr[am], bfr[kh][bn], acc[am][bn], 0, 0, 0);
        }
        __syncthreads();
    }

#pragma unroll
    for (int bn = 0; bn < 4; bn++) {
        int col = wave * 64 + bn * 16 + lr;
        float bv = isEnt ? 0.f : C2LOG2E * bias[col];
#pragma unroll
        for (int am = 0; am < 2; am++) {
#pragma unroll
            for (int rr = 0; rr < 4; rr++) {
                int row = m0 + am * 16 + lg * 4 + rr;
                if (row < M)
                    outp[(size_t)row * ldo + col] = f2bf(acc[am][bn][rr] + bv);
            }
        }
    }
}

// One wave per segment, 2 waves per block — r12/r18-EXACT body (best
// measured: fused 57.2-57.9us across 3 runs). Lane group g (16 lanes)
// handles neighbors j == 4*ji+g; lane covers 16 cols. Single pass, no
// max-subtraction (|score| <= ~10.2). proj & qpart pre-scaled by 2*log2e.
// Paired-rcp score: v0/(u0+1)+v1/(u1+1) = (v0*a1+v1*a0)*rcp(a0*a1), a=u+1.
// Gathers exec-predicated; proj+em prefetched 1-deep; ss/rr issued early.
// PLAIN 32-shfl cross-group combine (butterfly cost +9.5us, r14-r17).
// VGPR must stay <= 64 (cliff measured r14/r15: >64 costs ~35%).
__global__ void __launch_bounds__(128)
fused_agg_kernel(const int* __restrict__ nbr_ids,
                 const int* __restrict__ seg_start,
                 const unsigned short* __restrict__ comb,
                 const unsigned short* __restrict__ qpartbf,
                 const float* __restrict__ v_s,
                 const float* __restrict__ ent_embeds,
                 const float* __restrict__ rel_embeds,
                 const int* __restrict__ s,
                 const int* __restrict__ r,
                 float* __restrict__ out, int num_seg) {
    int seg = blockIdx.x * 2 + (threadIdx.x >> 6);
    if (seg >= num_seg) return;
    int lane = threadIdx.x & 63;
    int g = lane >> 4, li = lane & 15;
    int cb = li * 16;
    int c4 = lane * 4;
    int b = seg / SEQ;
    int start = seg_start[seg], end = seg_start[seg + 1];
    float* orow = out + (size_t)seg * (3 * H);

    if (start == end) {
        float4 z = {0.f, 0.f, 0.f, 0.f};
        *reinterpret_cast<float4*>(orow + c4) = z;
        *reinterpret_cast<float4*>(orow + H + c4) = z;
        *reinterpret_cast<float4*>(orow + 2 * H + c4) = z;
        return;
    }

    // issue ss/rr gathers early — consumed only at the end
    float4 ssv = *reinterpret_cast<const float4*>(ent_embeds + (size_t)s[b] * H + c4);
    float4 rrv = *reinterpret_cast<const float4*>(rel_embeds + (size_t)r[b] * H + c4);

    // v columns for this lane
    float vm2[16];  // -2*v
    float vsum = 0.f;
    {
        const float4* vp = reinterpret_cast<const float4*>(v_s + cb);
#pragma unroll
        for (int k = 0; k < 4; k++) {
            float4 tv = vp[k];
            vm2[4 * k + 0] = -2.f * tv.x; vm2[4 * k + 1] = -2.f * tv.y;
            vm2[4 * k + 2] = -2.f * tv.z; vm2[4 * k + 3] = -2.f * tv.w;
            vsum += tv.x + tv.y + tv.z + tv.w;
        }
    }

    float qv[16];
    {
        bf16x8 qa = *reinterpret_cast<const bf16x8*>(qpartbf + (size_t)b * H + cb);
        bf16x8 qb = *reinterpret_cast<const bf16x8*>(qpartbf + (size_t)b * H + cb + 8);
#pragma unroll
        for (int k = 0; k < 8; k++) {
            qv[k] = bf2f((unsigned short)qa[k]);
            qv[8 + k] = bf2f((unsigned short)qb[k]);
        }
    }

    float acc[16];
#pragma unroll
    for (int k = 0; k < 16; k++) acc[k] = 0.f;
    float lpart = 0.f;

    int cc = end - start;
    int nitm = (cc + 3) >> 2;

    // prologue: predicated load of row j=g (proj + em)
    bf16x8 p0 = {}, p1 = {}, e0 = {}, e1 = {};
    if (g < cc) {
        const unsigned short* row = comb + (size_t)nbr_ids[start + g] * 512 + cb;
        p0 = *reinterpret_cast<const bf16x8*>(row);
        p1 = *reinterpret_cast<const bf16x8*>(row + 8);
        e0 = *reinterpret_cast<const bf16x8*>(row + 256);
        e1 = *reinterpret_cast<const bf16x8*>(row + 264);
    }

    for (int ji = 0; ji < nitm; ji++) {
        // predicated prefetch of next row (proj + em)
        bf16x8 p0n = {}, p1n = {}, e0n = {}, e1n = {};
        int jn = 4 * (ji + 1) + g;
        if (jn < cc) {
            const unsigned short* rown = comb + (size_t)nbr_ids[start + jn] * 512 + cb;
            p0n = *reinterpret_cast<const bf16x8*>(rown);
            p1n = *reinterpret_cast<const bf16x8*>(rown + 8);
            e0n = *reinterpret_cast<const bf16x8*>(rown + 256);
            e1n = *reinterpret_cast<const bf16x8*>(rown + 264);
        }

        // paired-rcp score: 2 exp2 + 1 rcp per element pair
        float sa = 0.f, sb = 0.f;
#pragma unroll
        for (int k = 0; k < 8; k += 2) {
            float a0 = fexp2(bf2f((unsigned short)p0[k]) + qv[k]) + 1.f;
            float a1 = fexp2(bf2f((unsigned short)p1[k]) + qv[8 + k]) + 1.f;
            float num = vm2[k] * a1;
            num = fmaf(vm2[8 + k], a0, num);
            sa = fmaf(num, __builtin_amdgcn_rcpf(a0 * a1), sa);
            float b0 = fexp2(bf2f((unsigned short)p0[k + 1]) + qv[k + 1]) + 1.f;
            float b1 = fexp2(bf2f((unsigned short)p1[k + 1]) + qv[9 + k]) + 1.f;
            float numb = vm2[k + 1] * b1;
            numb = fmaf(vm2[9 + k], b0, numb);
            sb = fmaf(numb, __builtin_amdgcn_rcpf(b0 * b1), sb);
        }
        float s16 = sa + sb + vsum;
        s16 += __shfl_xor(s16, 1);
        s16 += __shfl_xor(s16, 2);
        s16 += __shfl_xor(s16, 4);
        s16 += __shfl_xor(s16, 8);
        float e = fexp2(s16 * LOG2E);
        e = (4 * ji + g < cc) ? e : 0.f;
        lpart += e;
#pragma unroll
        for (int k = 0; k < 8; k++) {
            acc[k] = fmaf(e, bf2f((unsigned short)e0[k]), acc[k]);
            acc[8 + k] = fmaf(e, bf2f((unsigned short)e1[k]), acc[8 + k]);
        }
        p0 = p0n; p1 = p1n; e0 = e0n; e1 = e1n;
    }

    // combine the 4 lane-groups (plain shfl — fastest measured)
    lpart += __shfl_xor(lpart, 16);
    lpart += __shfl_xor(lpart, 32);
#pragma unroll
    for (int k = 0; k < 16; k++) {
        acc[k] += __shfl_xor(acc[k], 16);
        acc[k] += __shfl_xor(acc[k], 32);
    }
    float invl = 1.f / lpart;

    // lane (g,li) writes cols cb + 4g .. cb+4g+3 (static selects)
    float4 o;
#pragma unroll
    for (int k = 0; k < 4; k++) {
        float v0 = acc[k], v1 = acc[4 + k], v2 = acc[8 + k], v3 = acc[12 + k];
        float pick = (g == 0) ? v0 : (g == 1) ? v1 : (g == 2) ? v2 : v3;
        if (k == 0) o.x = pick * invl;
        else if (k == 1) o.y = pick * invl;
        else if (k == 2) o.z = pick * invl;
        else o.w = pick * invl;
    }
    *reinterpret_cast<float4*>(orow + cb + 4 * g) = o;
    *reinterpret_cast<float4*>(orow + H + c4) = ssv;
    *reinterpret_cast<float4*>(orow + 2 * H + c4) = rrv;
}

extern "C" void kernel_launch(void* const* d_in, const int* in_sizes, int n_in,
                              void* d_out, int out_size, void* d_ws, size_t ws_size,
                              hipStream_t stream) {
    const int* s = (const int*)d_in[0];
    const int* r = (const int*)d_in[1];
    const int* nbr_ids = (const int*)d_in[2];
    const int* seg_ids = (const int*)d_in[3];
    const float* ent_embeds = (const float*)d_in[4];
    const float* rel_embeds = (const float*)d_in[5];
    const float* W_attn = (const float*)d_in[6];
    const float* b_attn = (const float*)d_in[7];
    const float* v_s = (const float*)d_in[8];
    float* out = (float*)d_out;

    int B = in_sizes[0];
    int N = in_sizes[2];
    int num_ent = in_sizes[4] / H;
    int num_seg = B * SEQ;

    char* ws = (char*)d_ws;
    unsigned short* comb = (unsigned short*)ws;                 // num_ent*512 (proj'|em)
    unsigned short* Wt = comb + (size_t)num_ent * 512;          // H*3H (pre-scaled)
    unsigned short* qpartbf = Wt + (size_t)H * 3 * H;           // B*H (pre-scaled)
    int* seg_start = (int*)(qpartbf + (size_t)B * H);           // num_seg+1

    prep_kernel<<<48, 256, 0, stream>>>(W_attn, Wt);

    int nEntBlk = (num_ent + 31) / 32;       // 625
    int nQBlk = B / 32;                      // 64
    int nSegBlk = (N + 255) / 256;           // 1280 (seg_start riders)
    gemm_bf16_kernel<<<nEntBlk + nQBlk + nSegBlk, 256, 0, stream>>>(
        ent_embeds, s, r, rel_embeds, Wt, b_attn, comb, qpartbf,
        seg_ids, seg_start, N, num_seg, nEntBlk, nQBlk, num_ent, B);

    fused_agg_kernel<<<(num_seg + 1) / 2, 128, 0, stream>>>(
        nbr_ids, seg_start, comb, qpartbf, v_s,
        ent_embeds, rel_embeds, s, r, out, num_seg);
}

// Round 21
// 88.990 us; speedup vs baseline: 1.2346x; 1.0019x over previous
//
#include <hip/hip_runtime.h>
#include <hip/hip_bf16.h>

#define H 256
#define SEQ 10
#define C2LOG2E 2.8853900817779268f   // 2*log2(e)
#define LOG2E 1.4426950408889634f

typedef __attribute__((ext_vector_type(8))) short bf16x8;
typedef __attribute__((ext_vector_type(4))) float f32x4;

__device__ __forceinline__ unsigned short f2bf(float x) {
    union { float f; unsigned u; } v; v.f = x;
    unsigned r = v.u + 0x7fff + ((v.u >> 16) & 1);  // RNE
    return (unsigned short)(r >> 16);
}
__device__ __forceinline__ float bf2f(unsigned short b) {
    union { unsigned u; float f; } v; v.u = ((unsigned)b) << 16;
    return v.f;
}
__device__ __forceinline__ float fexp2(float x) {
    return __builtin_amdgcn_exp2f(x);
}

// prep: 48 blocks, Wt via LDS tile transpose (coalesced both sides).
// Wt[n][k] = bf16(2log2e * W[k][n]), row-major [H][3H].
__global__ void prep_kernel(const float* __restrict__ W,
                            unsigned short* __restrict__ Wt) {
    __shared__ float tile[64][65];
    int tk = blockIdx.x % 12;   // k-tile (3H/64 = 12)
    int tn = blockIdx.x / 12;   // n-tile (H/64 = 4)
    int t = threadIdx.x;
    int rr = t >> 2;            // 0..63
    int rc = (t & 3) * 16;      // 0,16,32,48
    const float* src = W + (size_t)(tk * 64 + rr) * H + tn * 64 + rc;
    float4 a = *reinterpret_cast<const float4*>(src);
    float4 b = *reinterpret_cast<const float4*>(src + 4);
    float4 c = *reinterpret_cast<const float4*>(src + 8);
    float4 d = *reinterpret_cast<const float4*>(src + 12);
    tile[rr][rc + 0] = a.x;  tile[rr][rc + 1] = a.y;
    tile[rr][rc + 2] = a.z;  tile[rr][rc + 3] = a.w;
    tile[rr][rc + 4] = b.x;  tile[rr][rc + 5] = b.y;
    tile[rr][rc + 6] = b.z;  tile[rr][rc + 7] = b.w;
    tile[rr][rc + 8] = c.x;  tile[rr][rc + 9] = c.y;
    tile[rr][rc + 10] = c.z; tile[rr][rc + 11] = c.w;
    tile[rr][rc + 12] = d.x; tile[rr][rc + 13] = d.y;
    tile[rr][rc + 14] = d.z; tile[rr][rc + 15] = d.w;
    __syncthreads();
    bf16x8 o0, o1;
#pragma unroll
    for (int j = 0; j < 8; j++) {
        o0[j] = (short)f2bf(C2LOG2E * tile[rc + j][rr]);
        o1[j] = (short)f2bf(C2LOG2E * tile[rc + 8 + j][rr]);
    }
    unsigned short* dst = Wt + (size_t)(tn * 64 + rr) * (3 * H) + tk * 64 + rc;
    *reinterpret_cast<bf16x8*>(dst) = o0;
    *reinterpret_cast<bf16x8*>(dst + 8) = o1;
}

// Merged launch: GEMM blocks + seg_start rider blocks. GEMM: tile 32(m) x
// 256(n), BK=64, 4 waves — 625 ent + 64 qpart blocks (2.7/CU, small tail
// quantum; exact division). A staged via LDS; B (Wt, L2-hot) direct to regs.
// ent blocks: out=comb stride 512; staged bf16 A also written to comb em
// half. qpart blocks: A row m = [ent[s[m]]|rel[r[m]]], K=512, k0=H, +bias.
// NOTE (r20 lesson): Ep MUST stay bf16 — fp8 e4m3 overflows at exp2(proj')
// (max finite 448, NaN encodings) and even clamped gives catastrophic tanh
// errors when proj' clips while qpart' offsets it.
__global__ void gemm_bf16_kernel(const float* __restrict__ entf,
                                 const int* __restrict__ sidx,
                                 const int* __restrict__ ridx,
                                 const float* __restrict__ rel,
                                 const unsigned short* __restrict__ Wt,
                                 const float* __restrict__ bias,
                                 unsigned short* __restrict__ comb,
                                 unsigned short* __restrict__ qpart,
                                 const int* __restrict__ seg_ids,
                                 int* __restrict__ seg_start,
                                 int n, int num_seg,
                                 int nEntBlk, int nQBlk, int M0, int M1) {
    __shared__ unsigned short As[32][72];   // 64 k + 8 pad
    int bid = blockIdx.x;
    if (bid >= nEntBlk + nQBlk) {
        // seg_start rider blocks
        int j = (bid - nEntBlk - nQBlk) * 256 + threadIdx.x;
        if (j >= n) return;
        int cur = seg_ids[j];
        int prev = (j == 0) ? -1 : seg_ids[j - 1];
        for (int s2 = prev + 1; s2 <= cur; s2++) seg_start[s2] = j;
        if (j == n - 1)
            for (int s2 = cur + 1; s2 <= num_seg; s2++) seg_start[s2] = n;
        return;
    }

    bool isEnt = bid < nEntBlk;
    int m0 = (isEnt ? bid : (bid - nEntBlk)) * 32;
    int M = isEnt ? M0 : M1;
    int K = isEnt ? H : 2 * H;
    int k0 = isEnt ? 0 : H;
    int ldo = isEnt ? 512 : H;
    unsigned short* outp = isEnt ? comb : qpart;

    int t = threadIdx.x;
    int sr = t >> 3;          // staging row 0..31
    int sc = (t & 7) * 8;     // staging k-offset 0,8,..56
    int wave = t >> 6, lane = t & 63;
    int lr = lane & 15, lg = lane >> 4;

    f32x4 acc[2][4];
#pragma unroll
    for (int i = 0; i < 2; i++)
#pragma unroll
        for (int jn = 0; jn < 4; jn++) acc[i][jn] = (f32x4){0.f, 0.f, 0.f, 0.f};

    const unsigned short* bp[4];
#pragma unroll
    for (int bn = 0; bn < 4; bn++)
        bp[bn] = Wt + (size_t)(wave * 64 + bn * 16 + lr) * (3 * H) + k0 + lg * 8;

    for (int kk = 0; kk < K; kk += 64) {
        bf16x8 av = {};
        int gm = m0 + sr;
        if (gm < M) {
            const float* src;
            if (isEnt) {
                src = entf + (size_t)gm * H + kk + sc;
            } else {
                int k = kk + sc;
                src = (k < H) ? (entf + (size_t)sidx[gm] * H + k)
                              : (rel + (size_t)ridx[gm] * H + (k - H));
            }
            float4 f0 = *reinterpret_cast<const float4*>(src);
            float4 f1 = *reinterpret_cast<const float4*>(src + 4);
            av[0] = (short)f2bf(f0.x); av[1] = (short)f2bf(f0.y);
            av[2] = (short)f2bf(f0.z); av[3] = (short)f2bf(f0.w);
            av[4] = (short)f2bf(f1.x); av[5] = (short)f2bf(f1.y);
            av[6] = (short)f2bf(f1.z); av[7] = (short)f2bf(f1.w);
            if (isEnt)
                *reinterpret_cast<bf16x8*>(comb + (size_t)gm * 512 + 256 + kk + sc) = av;
        }
        *reinterpret_cast<bf16x8*>(&As[sr][sc]) = av;

        // B fragments direct from global (L2-hot): 2 k-halves x 4 col-frags
        bf16x8 bfr[2][4];
#pragma unroll
        for (int kh = 0; kh < 2; kh++)
#pragma unroll
            for (int bn = 0; bn < 4; bn++)
                bfr[kh][bn] = *reinterpret_cast<const bf16x8*>(bp[bn] + kk + kh * 32);

        __syncthreads();
#pragma unroll
        for (int kh = 0; kh < 2; kh++) {
            bf16x8 afr[2];
#pragma unroll
            for (int am = 0; am < 2; am++)
                afr[am] = *reinterpret_cast<const bf16x8*>(&As[am * 16 + lr][kh * 32 + lg * 8]);
#pragma unroll
            for (int am = 0; am < 2; am++)
#pragma unroll
                for (int bn = 0; bn < 4; bn++)
                    acc[am][bn] = __builtin_amdgcn_mfma_f32_16x16x32_bf16(
                        afr[am], bfr[kh][bn], acc[am][bn], 0, 0, 0);
        }
        __syncthreads();
    }

#pragma unroll
    for (int bn = 0; bn < 4; bn++) {
        int col = wave * 64 + bn * 16 + lr;
        float bv = isEnt ? 0.f : C2LOG2E * bias[col];
#pragma unroll
        for (int am = 0; am < 2; am++) {
#pragma unroll
            for (int rr = 0; rr < 4; rr++) {
                int row = m0 + am * 16 + lg * 4 + rr;
                if (row < M)
                    outp[(size_t)row * ldo + col] = f2bf(acc[am][bn][rr] + bv);
            }
        }
    }
}

// One wave per segment, 2 waves per block — floor-verified body (fused
// 57.2-58.2us across r12/r18/r19 with identical counters; memory-bound at
// ~93% of the blended gather-service ceiling). Lane group g (16 lanes)
// handles neighbors j == 4*ji+g; lane covers 16 cols. Single pass, no
// max-subtraction (|score| <= ~10.2). proj & qpart pre-scaled by 2*log2e.
// Paired-rcp score: v0/(u0+1)+v1/(u1+1) = (v0*a1+v1*a0)*rcp(a0*a1), a=u+1.
// Gathers exec-predicated; proj+em prefetched 1-deep; ss/rr issued early.
// PLAIN 32-shfl cross-group combine (butterfly cost +9.5us, r14-r17).
// VGPR must stay <= 64 (cliff measured r14/r15: >64 costs ~35%).
__global__ void __launch_bounds__(128)
fused_agg_kernel(const int* __restrict__ nbr_ids,
                 const int* __restrict__ seg_start,
                 const unsigned short* __restrict__ comb,
                 const unsigned short* __restrict__ qpartbf,
                 const float* __restrict__ v_s,
                 const float* __restrict__ ent_embeds,
                 const float* __restrict__ rel_embeds,
                 const int* __restrict__ s,
                 const int* __restrict__ r,
                 float* __restrict__ out, int num_seg) {
    int seg = blockIdx.x * 2 + (threadIdx.x >> 6);
    if (seg >= num_seg) return;
    int lane = threadIdx.x & 63;
    int g = lane >> 4, li = lane & 15;
    int cb = li * 16;
    int c4 = lane * 4;
    int b = seg / SEQ;
    int start = seg_start[seg], end = seg_start[seg + 1];
    float* orow = out + (size_t)seg * (3 * H);

    if (start == end) {
        float4 z = {0.f, 0.f, 0.f, 0.f};
        *reinterpret_cast<float4*>(orow + c4) = z;
        *reinterpret_cast<float4*>(orow + H + c4) = z;
        *reinterpret_cast<float4*>(orow + 2 * H + c4) = z;
        return;
    }

    // issue ss/rr gathers early — consumed only at the end
    float4 ssv = *reinterpret_cast<const float4*>(ent_embeds + (size_t)s[b] * H + c4);
    float4 rrv = *reinterpret_cast<const float4*>(rel_embeds + (size_t)r[b] * H + c4);

    // v columns for this lane
    float vm2[16];  // -2*v
    float vsum = 0.f;
    {
        const float4* vp = reinterpret_cast<const float4*>(v_s + cb);
#pragma unroll
        for (int k = 0; k < 4; k++) {
            float4 tv = vp[k];
            vm2[4 * k + 0] = -2.f * tv.x; vm2[4 * k + 1] = -2.f * tv.y;
            vm2[4 * k + 2] = -2.f * tv.z; vm2[4 * k + 3] = -2.f * tv.w;
            vsum += tv.x + tv.y + tv.z + tv.w;
        }
    }

    float qv[16];
    {
        bf16x8 qa = *reinterpret_cast<const bf16x8*>(qpartbf + (size_t)b * H + cb);
        bf16x8 qb = *reinterpret_cast<const bf16x8*>(qpartbf + (size_t)b * H + cb + 8);
#pragma unroll
        for (int k = 0; k < 8; k++) {
            qv[k] = bf2f((unsigned short)qa[k]);
            qv[8 + k] = bf2f((unsigned short)qb[k]);
        }
    }

    float acc[16];
#pragma unroll
    for (int k = 0; k < 16; k++) acc[k] = 0.f;
    float lpart = 0.f;

    int cc = end - start;
    int nitm = (cc + 3) >> 2;

    // prologue: predicated load of row j=g (proj + em)
    bf16x8 p0 = {}, p1 = {}, e0 = {}, e1 = {};
    if (g < cc) {
        const unsigned short* row = comb + (size_t)nbr_ids[start + g] * 512 + cb;
        p0 = *reinterpret_cast<const bf16x8*>(row);
        p1 = *reinterpret_cast<const bf16x8*>(row + 8);
        e0 = *reinterpret_cast<const bf16x8*>(row + 256);
        e1 = *reinterpret_cast<const bf16x8*>(row + 264);
    }

    for (int ji = 0; ji < nitm; ji++) {
        // predicated prefetch of next row (proj + em)
        bf16x8 p0n = {}, p1n = {}, e0n = {}, e1n = {};
        int jn = 4 * (ji + 1) + g;
        if (jn < cc) {
            const unsigned short* rown = comb + (size_t)nbr_ids[start + jn] * 512 + cb;
            p0n = *reinterpret_cast<const bf16x8*>(rown);
            p1n = *reinterpret_cast<const bf16x8*>(rown + 8);
            e0n = *reinterpret_cast<const bf16x8*>(rown + 256);
            e1n = *reinterpret_cast<const bf16x8*>(rown + 264);
        }

        // paired-rcp score: 2 exp2 + 1 rcp per element pair
        float sa = 0.f, sb = 0.f;
#pragma unroll
        for (int k = 0; k < 8; k += 2) {
            float a0 = fexp2(bf2f((unsigned short)p0[k]) + qv[k]) + 1.f;
            float a1 = fexp2(bf2f((unsigned short)p1[k]) + qv[8 + k]) + 1.f;
            float num = vm2[k] * a1;
            num = fmaf(vm2[8 + k], a0, num);
            sa = fmaf(num, __builtin_amdgcn_rcpf(a0 * a1), sa);
            float b0 = fexp2(bf2f((unsigned short)p0[k + 1]) + qv[k + 1]) + 1.f;
            float b1 = fexp2(bf2f((unsigned short)p1[k + 1]) + qv[9 + k]) + 1.f;
            float numb = vm2[k + 1] * b1;
            numb = fmaf(vm2[9 + k], b0, numb);
            sb = fmaf(numb, __builtin_amdgcn_rcpf(b0 * b1), sb);
        }
        float s16 = sa + sb + vsum;
        s16 += __shfl_xor(s16, 1);
        s16 += __shfl_xor(s16, 2);
        s16 += __shfl_xor(s16, 4);
        s16 += __shfl_xor(s16, 8);
        float e = fexp2(s16 * LOG2E);
        e = (4 * ji + g < cc) ? e : 0.f;
        lpart += e;
#pragma unroll
        for (int k = 0; k < 8; k++) {
            acc[k] = fmaf(e, bf2f((unsigned short)e0[k]), acc[k]);
            acc[8 + k] = fmaf(e, bf2f((unsigned short)e1[k]), acc[8 + k]);
        }
        p0 = p0n; p1 = p1n; e0 = e0n; e1 = e1n;
    }

    // combine the 4 lane-groups (plain shfl — fastest measured)
    lpart += __shfl_xor(lpart, 16);
    lpart += __shfl_xor(lpart, 32);
#pragma unroll
    for (int k = 0; k < 16; k++) {
        acc[k] += __shfl_xor(acc[k], 16);
        acc[k] += __shfl_xor(acc[k], 32);
    }
    float invl = 1.f / lpart;

    // lane (g,li) writes cols cb + 4g .. cb+4g+3 (static selects)
    float4 o;
#pragma unroll
    for (int k = 0; k < 4; k++) {
        float v0 = acc[k], v1 = acc[4 + k], v2 = acc[8 + k], v3 = acc[12 + k];
        float pick = (g == 0) ? v0 : (g == 1) ? v1 : (g == 2) ? v2 : v3;
        if (k == 0) o.x = pick * invl;
        else if (k == 1) o.y = pick * invl;
        else if (k == 2) o.z = pick * invl;
        else o.w = pick * invl;
    }
    *reinterpret_cast<float4*>(orow + cb + 4 * g) = o;
    *reinterpret_cast<float4*>(orow + H + c4) = ssv;
    *reinterpret_cast<float4*>(orow + 2 * H + c4) = rrv;
}

extern "C" void kernel_launch(void* const* d_in, const int* in_sizes, int n_in,
                              void* d_out, int out_size, void* d_ws, size_t ws_size,
                              hipStream_t stream) {
    const int* s = (const int*)d_in[0];
    const int* r = (const int*)d_in[1];
    const int* nbr_ids = (const int*)d_in[2];
    const int* seg_ids = (const int*)d_in[3];
    const float* ent_embeds = (const float*)d_in[4];
    const float* rel_embeds = (const float*)d_in[5];
    const float* W_attn = (const float*)d_in[6];
    const float* b_attn = (const float*)d_in[7];
    const float* v_s = (const float*)d_in[8];
    float* out = (float*)d_out;

    int B = in_sizes[0];
    int N = in_sizes[2];
    int num_ent = in_sizes[4] / H;
    int num_seg = B * SEQ;

    char* ws = (char*)d_ws;
    unsigned short* comb = (unsigned short*)ws;                 // num_ent*512 (proj'|em)
    unsigned short* Wt = comb + (size_t)num_ent * 512;          // H*3H (pre-scaled)
    unsigned short* qpartbf = Wt + (size_t)H * 3 * H;           // B*H (pre-scaled)
    int* seg_start = (int*)(qpartbf + (size_t)B * H);           // num_seg+1

    prep_kernel<<<48, 256, 0, stream>>>(W_attn, Wt);

    int nEntBlk = (num_ent + 31) / 32;       // 625
    int nQBlk = B / 32;                      // 64
    int nSegBlk = (N + 255) / 256;           // 1280 (seg_start riders)
    gemm_bf16_kernel<<<nEntBlk + nQBlk + nSegBlk, 256, 0, stream>>>(
        ent_embeds, s, r, rel_embeds, Wt, b_attn, comb, qpartbf,
        seg_ids, seg_start, N, num_seg, nEntBlk, nQBlk, num_ent, B);

    fused_agg_kernel<<<(num_seg + 1) / 2, 128, 0, stream>>>(
        nbr_ids, seg_start, comb, qpartbf, v_s,
        ent_embeds, rel_embeds, s, r, out, num_seg);
}